// Round 9
// baseline (293.195 us; speedup 1.0000x reference)
//
#include <hip/hip_runtime.h>
#include <stdint.h>

typedef unsigned short u16;
typedef __attribute__((ext_vector_type(8))) short bh8;   // 8 bf16 = 4 VGPR
typedef __attribute__((ext_vector_type(4))) float f4;    // MFMA acc

#define LOG2E 1.44269504088896f
#define QSCALE 0.18033688f   // 0.125 * log2(e), folded into Q at GEMM1 epilogue

__device__ inline u16 f2bf(float f) {
  union { float f; uint32_t u; } c; c.f = f;
  uint32_t u = c.u;
  return (u16)((u + 0x7fffu + ((u >> 16) & 1u)) >> 16);  // RNE
}

__device__ inline float fast_exp2(float x) {
#if __has_builtin(__builtin_amdgcn_exp2f)
  return __builtin_amdgcn_exp2f(x);
#else
  return exp2f(x);
#endif
}

#if __has_builtin(__builtin_amdgcn_global_load_lds)
#define GLD16(gp, lp) __builtin_amdgcn_global_load_lds( \
    (const __attribute__((address_space(1))) void*)(gp), \
    (__attribute__((address_space(3))) void*)(lp), 16, 0, 0)
#else
#define GLD16(gp, lp) do { *(bh8*)(lp) = *(const bh8*)(gp); } while (0)
#endif

// ---------------- convert / transpose ----------------

__global__ __launch_bounds__(256) void cvt_f32_bf16(const float* __restrict__ src,
                                                    u16* __restrict__ dst, int n4) {
  int i = blockIdx.x * 256 + threadIdx.x;
  if (i < n4) {
    float4 v = ((const float4*)src)[i];
    ushort4 o;
    o.x = f2bf(v.x); o.y = f2bf(v.y); o.z = f2bf(v.z); o.w = f2bf(v.w);
    ((ushort4*)dst)[i] = o;
  }
}

// src: K x N fp32 row-major -> dst: N x K bf16 row-major
__global__ __launch_bounds__(1024) void transpose_cvt(const float* __restrict__ src,
                                                      u16* __restrict__ dst, int K, int N) {
  __shared__ float tile[32][33];
  int n0 = blockIdx.x * 32, k0 = blockIdx.y * 32;
  int tx = threadIdx.x, ty = threadIdx.y;
  tile[ty][tx] = src[(size_t)(k0 + ty) * N + n0 + tx];
  __syncthreads();
  dst[(size_t)(n0 + ty) * K + k0 + tx] = f2bf(tile[tx][ty]);
}

// v [64][2048][64] bf16 -> vt [64][64][2048] bf16
__global__ __launch_bounds__(1024) void transpose_b16(const u16* __restrict__ src,
                                                      u16* __restrict__ dst) {
  __shared__ u16 t[32][33];
  int bh = blockIdx.z, l0 = blockIdx.y * 32, d0 = blockIdx.x * 32;
  int tx = threadIdx.x, ty = threadIdx.y;
  t[ty][tx] = src[((size_t)bh * 2048 + l0 + ty) * 64 + d0 + tx];
  __syncthreads();
  dst[((size_t)bh * 64 + d0 + ty) * 2048 + l0 + tx] = t[tx][ty];
}

// ---------------- GEMM mainloop (C = A @ Bt^T), 128x128 tile, BK=64 ----------------
__device__ inline void gemm_mainloop(const u16* __restrict__ A, const u16* __restrict__ Bt,
                                     int K, int m0, int n0,
                                     u16* As, u16* Bs, f4 acc[4][4]) {
  const int tid  = threadIdx.x;
  const int lane = tid & 63;
  const int quad = lane >> 4;
  const int ml   = lane & 15;
  const int wave = tid >> 6;
  const int wm   = (wave >> 1) * 64;
  const int wn   = (wave & 1) * 64;

#pragma unroll 1
  for (int k0 = 0; k0 < K; k0 += 64) {
#pragma unroll
    for (int r = 0; r < 4; ++r) {
      int chunk = r * 256 + tid;
      int row = chunk >> 3, cc = chunk & 7;
      int cg = cc ^ (row & 7);
      GLD16(A + (size_t)(m0 + row) * K + k0 + cg * 8, As + chunk * 8);
    }
#pragma unroll
    for (int r = 0; r < 4; ++r) {
      int chunk = r * 256 + tid;
      int row = chunk >> 3, cc = chunk & 7;
      int cg = cc ^ (row & 7);
      GLD16(Bt + (size_t)(n0 + row) * K + k0 + cg * 8, Bs + chunk * 8);
    }
    __syncthreads();
#pragma unroll
    for (int ks = 0; ks < 2; ++ks) {
      bh8 af[4], bfr[4];
      int cs = (ks * 4 + quad) ^ (ml & 7);
#pragma unroll
      for (int i = 0; i < 4; ++i) {
        int row = wm + i * 16 + ml;
        af[i] = *(const bh8*)(As + (row * 8 + cs) * 8);
      }
#pragma unroll
      for (int j = 0; j < 4; ++j) {
        int row = wn + j * 16 + ml;
        bfr[j] = *(const bh8*)(Bs + (row * 8 + cs) * 8);
      }
#pragma unroll
      for (int i = 0; i < 4; ++i)
#pragma unroll
        for (int j = 0; j < 4; ++j)
          acc[i][j] = __builtin_amdgcn_mfma_f32_16x16x32_bf16(af[i], bfr[j], acc[i][j], 0, 0, 0);
    }
    __syncthreads();
  }
}

// ---------------- GEMM1: qkv = x @ w_qkv + b ----------------
// q scaled by QSCALE; q,k,v all stored [bh][l][d] bf16 (v transposed later)
__global__ __launch_bounds__(256) void gemm_qkv(const u16* __restrict__ xb,
                                                const u16* __restrict__ wqt,
                                                const float* __restrict__ bqkv,
                                                u16* __restrict__ q, u16* __restrict__ k,
                                                u16* __restrict__ v) {
  __shared__ __align__(16) u16 smem[2 * 128 * 64];
  const f4 fzero = {0.f, 0.f, 0.f, 0.f};
  f4 acc[4][4];
#pragma unroll
  for (int i = 0; i < 4; ++i)
#pragma unroll
    for (int j = 0; j < 4; ++j) acc[i][j] = fzero;

  int m0 = blockIdx.y * 128, n0 = blockIdx.x * 128;
  gemm_mainloop(xb, wqt, 1024, m0, n0, smem, smem + 128 * 64, acc);

  const int lane = threadIdx.x & 63, wave = threadIdx.x >> 6;
  const int quad = lane >> 4, ml = lane & 15;
  const int wm = (wave >> 1) * 64, wn = (wave & 1) * 64;
  u16* dst = (n0 < 1024) ? q : ((n0 < 2048) ? k : v);
  float scale = (n0 < 1024) ? QSCALE : 1.0f;
#pragma unroll
  for (int j = 0; j < 4; ++j) {
    int nn = n0 + wn + j * 16 + ml;
    int h = (nn >> 6) & 15, d = nn & 63;
    float bias = bqkv[nn];
#pragma unroll
    for (int i = 0; i < 4; ++i) {
#pragma unroll
      for (int r = 0; r < 4; ++r) {
        int tok = m0 + wm + i * 16 + quad * 4 + r;
        int b = tok >> 11, l = tok & 2047;
        int bh = b * 16 + h;
        dst[((size_t)bh * 2048 + l) * 64 + d] = f2bf((acc[i][j][r] + bias) * scale);
      }
    }
  }
}

// ---------------- GEMM2: out = o @ w_out + b_out (fp32 out), 64x128 tile -----------
// Round-8 postmortem: old gemm_out ran grid (8,64) = 512 wg = 2 blocks/CU = 8
// waves/CU -- the same occupancy starvation that limited attn; the per-K-step
// staging drain was exposed. Retile to BM=64 x BN=128: grid (8,128) = 1024 wg =
// 4 blocks/CU (16 waves/CU), LDS 24KB. Same proven staging/swizzle/fragment
// pattern as gemm_mainloop, re-parameterized.
__global__ __launch_bounds__(256) void gemm_out64(const u16* __restrict__ ob,
                                                  const u16* __restrict__ wot,
                                                  const float* __restrict__ bout,
                                                  float* __restrict__ out) {
  __shared__ __align__(16) u16 As[64 * 64];
  __shared__ __align__(16) u16 Bs[128 * 64];
  const int tid  = threadIdx.x;
  const int lane = tid & 63;
  const int quad = lane >> 4;
  const int ml   = lane & 15;
  const int wave = tid >> 6;
  const int wm   = (wave >> 1) * 32;   // 2 wave-rows x 32
  const int wn   = (wave & 1) * 64;    // 2 wave-cols x 64
  const int m0 = blockIdx.y * 64, n0 = blockIdx.x * 128;

  const f4 fzero = {0.f, 0.f, 0.f, 0.f};
  f4 acc[2][4];
#pragma unroll
  for (int i = 0; i < 2; ++i)
#pragma unroll
    for (int j = 0; j < 4; ++j) acc[i][j] = fzero;

  const int srow = tid >> 3, scc = tid & 7;
  const int scg = scc ^ (srow & 7);

#pragma unroll 1
  for (int k0 = 0; k0 < 1024; k0 += 64) {
#pragma unroll
    for (int r = 0; r < 2; ++r) {
      int row = r * 32 + srow;   // [0,64)
      GLD16(ob + (size_t)(m0 + row) * 1024 + k0 + scg * 8, As + (row * 8 + scc) * 8);
    }
#pragma unroll
    for (int r = 0; r < 4; ++r) {
      int row = r * 32 + srow;   // [0,128)
      GLD16(wot + (size_t)(n0 + row) * 1024 + k0 + scg * 8, Bs + (row * 8 + scc) * 8);
    }
    __syncthreads();
#pragma unroll
    for (int ks = 0; ks < 2; ++ks) {
      int cs = (ks * 4 + quad) ^ (ml & 7);
      bh8 af[2], bfr[4];
#pragma unroll
      for (int i = 0; i < 2; ++i)
        af[i] = *(const bh8*)(As + ((wm + i * 16 + ml) * 8 + cs) * 8);
#pragma unroll
      for (int j = 0; j < 4; ++j)
        bfr[j] = *(const bh8*)(Bs + ((wn + j * 16 + ml) * 8 + cs) * 8);
#pragma unroll
      for (int i = 0; i < 2; ++i)
#pragma unroll
        for (int j = 0; j < 4; ++j)
          acc[i][j] = __builtin_amdgcn_mfma_f32_16x16x32_bf16(af[i], bfr[j], acc[i][j], 0, 0, 0);
    }
    __syncthreads();
  }

#pragma unroll
  for (int j = 0; j < 4; ++j) {
    int nn = n0 + wn + j * 16 + ml;
    float bias = bout[nn];
#pragma unroll
    for (int i = 0; i < 2; ++i)
#pragma unroll
      for (int r = 0; r < 4; ++r) {
        int tok = m0 + wm + i * 16 + quad * 4 + r;
        out[(size_t)tok * 1024 + nn] = acc[i][j][r] + bias;
      }
  }
}

// ---------------- flash attention v11: conflict-free Pq ----------------------------
// Round-8 postmortem: v10's 4.19M bank conflicts = exactly 32 cyc/tile/wave, from
// the Pq swizzle XORing only ml&14 -> within a 16-lane b64 phase group (fixed quad)
// lanes ml/ml+1 share a bank pair (2-way). v8-vs-v10 pair hardware-validates the
// conflict domain: 16 consecutive lanes for b64 DS ops. Fix: slot index XORs FULL ml
// (bijective per phase group -> all 32 banks hit exactly once), and the pf read
// becomes 2x ds_read_b64 at exact slots (b128 would need pair-aligned slots, which
// contradicts full-ml bijectivity). Key mapping verified: read s0=(g*8+2quad)^ml
// yields keys-in-half 8quad..+3 (from write jl=quad>>1, qw=2(quad&1)), s1 yields
// 8quad+4..+7 -> pf ascending = B[k=ks*32+8quad+e][ml] as the PV B-fragment needs.
// Everything else identical to v10 (passed, 99.3us).
__global__ __launch_bounds__(256, 4) void attn(const u16* __restrict__ q,
                                               const u16* __restrict__ k,
                                               const u16* __restrict__ vt,
                                               u16* __restrict__ o) {
  __shared__ __align__(16) u16 Ks[2][64 * 64];    // row=key, 8 chunks, XOR swizzle
  __shared__ __align__(16) u16 Vs[2][64 * 64];    // row=d,   cols=key, XOR swizzle
  __shared__ __align__(16) u16 Pq[4][16 * 64];    // per-wave P, per-ml 128B regions
  const int bh = blockIdx.x;
  const int b = bh >> 4, h = bh & 15;
  const int tid = threadIdx.x;
  const int wave = tid >> 6, lane = tid & 63;
  const int quad = lane >> 4, ml = lane & 15;
  const int qw = blockIdx.y * 128 + wave * 32;
  const u16* qp = q + (size_t)bh * 2048 * 64;
  const u16* kp = k + (size_t)bh * 2048 * 64;
  const u16* vp = vt + (size_t)bh * 64 * 2048;
  const f4 fzero = {0.f, 0.f, 0.f, 0.f};

  const int mlx = ml & 7;    // XOR bits for Ks/Vs 16B-chunk swizzle

  // Q fragments: B-operand, rows qw+g*16+ml, 16B contiguous
  bh8 qf[2][2];
#pragma unroll
  for (int g = 0; g < 2; ++g)
#pragma unroll
    for (int ks = 0; ks < 2; ++ks)
      qf[g][ks] = *(const bh8*)&qp[(size_t)(qw + g * 16 + ml) * 64 + ks * 32 + quad * 8];

  f4 oacc[2][4];
#pragma unroll
  for (int g = 0; g < 2; ++g)
#pragma unroll
    for (int j = 0; j < 4; ++j) oacc[g][j] = fzero;
  float lsum[2] = {0.f, 0.f};

  // staging addresses (row/chunk decomposition identical to gemm_mainloop)
  const int srow = tid >> 3, scc = tid & 7;
  const int scg = scc ^ (srow & 7);
  u16* pq = &Pq[wave][ml * 64];   // this lane's 128B region: 16 slots x 8B

  // prologue: stage K+V tile 0 into buffer 0
#pragma unroll
  for (int r = 0; r < 2; ++r) {
    int row = r * 32 + srow;
    GLD16(kp + (size_t)row * 64 + scg * 8, &Ks[0][(row * 8 + scc) * 8]);
    GLD16(vp + (size_t)row * 2048 + scg * 8, &Vs[0][(row * 8 + scc) * 8]);
  }
  __syncthreads();

  int cur = 0;
#pragma unroll 1
  for (int t = 0; t < 32; ++t) {
    // stage next K+V tile into the other buffer (in flight until end-of-tile drain)
    if (t < 31) {
      int ktn = (t + 1) * 64;
#pragma unroll
      for (int r = 0; r < 2; ++r) {
        int row = r * 32 + srow;
        GLD16(kp + (size_t)(ktn + row) * 64 + scg * 8, &Ks[cur ^ 1][(row * 8 + scc) * 8]);
        GLD16(vp + (size_t)row * 2048 + ktn + scg * 8, &Vs[cur ^ 1][(row * 8 + scc) * 8]);
      }
    }

    // S^T = K @ Q^T from LDS: s[g][j][r] = S[q=qw+g*16+ml][kt + 16j + 4quad + r]
    f4 s[2][4];
#pragma unroll
    for (int g = 0; g < 2; ++g)
#pragma unroll
      for (int j = 0; j < 4; ++j) s[g][j] = fzero;
#pragma unroll
    for (int ks = 0; ks < 2; ++ks) {
      int cs = (ks * 4 + quad) ^ mlx;
      bh8 kf[4];
#pragma unroll
      for (int j = 0; j < 4; ++j)
        kf[j] = *(const bh8*)(&Ks[cur][((j * 16 + ml) * 8 + cs) * 8]);
#pragma unroll
      for (int j = 0; j < 4; ++j) {
        s[0][j] = __builtin_amdgcn_mfma_f32_16x16x32_bf16(kf[j], qf[0][ks], s[0][j], 0, 0, 0);
        s[1][j] = __builtin_amdgcn_mfma_f32_16x16x32_bf16(kf[j], qf[1][ks], s[1][j], 0, 0, 0);
      }
    }

    // two ks-phases: softmax keys [32ks,32ks+32) -> write -> pf read -> PV.
    // Pq slots reused across phases (same-wave DS in-order => WAR safe).
#pragma unroll
    for (int ks = 0; ks < 2; ++ks) {
      // p = exp2(s) -> bf16 (half-up, proven bit path); lsum from the SAME rounded
      // values so numerator/denominator rounding bias cancels exactly.
#pragma unroll
      for (int g = 0; g < 2; ++g) {
#pragma unroll
        for (int jl = 0; jl < 2; ++jl) {
          int j = ks * 2 + jl;
          uint32_t w[4];
#pragma unroll
          for (int r = 0; r < 4; ++r) {
            float p = fast_exp2(s[g][j][r]);
            union { float f; uint32_t u; } c; c.f = p;
            c.u = (c.u + 0x8000u) & 0xFFFF0000u;
            lsum[g] += c.f;
            w[r] = c.u;
          }
          uint2 pk;
          pk.x = (w[0] >> 16) | w[1];
          pk.y = (w[2] >> 16) | w[3];
          int sl = (g * 8 + jl * 4 + quad) ^ ml;    // bijective in ml per phase group
          *(uint2*)(pq + (sl << 2)) = pk;
        }
      }

      // O^T += V^T @ P^T: vf from LDS (read once per ks, reused for both groups);
      // pf via two b64 reads at exact slots (conflict-free, ascending key order).
      int cs = (ks * 4 + quad) ^ mlx;
      bh8 vf[4];
#pragma unroll
      for (int j = 0; j < 4; ++j)
        vf[j] = *(const bh8*)(&Vs[cur][((j * 16 + ml) * 8 + cs) * 8]);
#pragma unroll
      for (int g = 0; g < 2; ++g) {
        int s0 = (g * 8 + 2 * quad) ^ ml;
        int s1 = (g * 8 + 2 * quad + 1) ^ ml;
        uint2 lo = *(const uint2*)(pq + (s0 << 2));
        uint2 hi = *(const uint2*)(pq + (s1 << 2));
        union { uint32_t u[4]; bh8 v; } pf;
        pf.u[0] = lo.x; pf.u[1] = lo.y; pf.u[2] = hi.x; pf.u[3] = hi.y;
#pragma unroll
        for (int j = 0; j < 4; ++j)
          oacc[g][j] = __builtin_amdgcn_mfma_f32_16x16x32_bf16(vf[j], pf.v, oacc[g][j], 0, 0, 0);
      }
    }
    __syncthreads();   // drains K/V stage (vmcnt) + all LDS reads of buf[cur]
    cur ^= 1;
  }

  // li: lane-local partial covers keys {16j+4quad+r}; reduce across quads
#pragma unroll
  for (int g = 0; g < 2; ++g) {
    lsum[g] += __shfl_xor(lsum[g], 16, 64);
    lsum[g] += __shfl_xor(lsum[g], 32, 64);
    float inv = 1.0f / lsum[g];
    // store o as (b, l, h, d) bf16; lane holds q=qw+g*16+ml, d=16j+4quad+r
    size_t obase = (((size_t)b * 2048 + qw + g * 16 + ml) * 16 + h) * 64;
#pragma unroll
    for (int j = 0; j < 4; ++j) {
      ushort4 w;
      w.x = f2bf(oacc[g][j][0] * inv);
      w.y = f2bf(oacc[g][j][1] * inv);
      w.z = f2bf(oacc[g][j][2] * inv);
      w.w = f2bf(oacc[g][j][3] * inv);
      *(ushort4*)(o + obase + j * 16 + quad * 4) = w;
    }
  }
}

// ---------------- launch ----------------

extern "C" void kernel_launch(void* const* d_in, const int* in_sizes, int n_in,
                              void* d_out, int out_size, void* d_ws, size_t ws_size,
                              hipStream_t stream) {
  const float* x     = (const float*)d_in[0];
  const float* w_qkv = (const float*)d_in[1];
  const float* b_qkv = (const float*)d_in[2];
  const float* w_out = (const float*)d_in[3];
  const float* b_out = (const float*)d_in[4];
  float* out = (float*)d_out;

  u16* ws  = (u16*)d_ws;
  u16* xb  = ws;                                  // 8192*1024 (later reused for vt)
  u16* wqt = xb + (size_t)8192 * 1024;            // 3072*1024
  u16* wot = wqt + (size_t)3072 * 1024;           // 1024*1024
  u16* qb  = wot + (size_t)1024 * 1024;           // 64*2048*64
  u16* kb  = qb + (size_t)64 * 2048 * 64;
  u16* vb  = kb + (size_t)64 * 2048 * 64;
  u16* vtb = xb;   // xb dead after gemm_qkv
  u16* ob  = vb;   // v dead after transpose_b16

  cvt_f32_bf16<<<8192, 256, 0, stream>>>(x, xb, 8192 * 1024 / 4);
  transpose_cvt<<<dim3(96, 32), dim3(32, 32), 0, stream>>>(w_qkv, wqt, 1024, 3072);
  transpose_cvt<<<dim3(32, 32), dim3(32, 32), 0, stream>>>(w_out, wot, 1024, 1024);
  gemm_qkv<<<dim3(24, 64), 256, 0, stream>>>(xb, wqt, b_qkv, qb, kb, vb);
  transpose_b16<<<dim3(2, 64, 64), dim3(32, 32), 0, stream>>>(vb, vtb);
  attn<<<dim3(64, 16), 256, 0, stream>>>(qb, kb, vtb, ob);
  gemm_out64<<<dim3(8, 128), 256, 0, stream>>>(ob, wot, b_out, out);
}

// Round 11
// 287.321 us; speedup vs baseline: 1.0204x; 1.0204x over previous
//
#include <hip/hip_runtime.h>
#include <stdint.h>

typedef unsigned short u16;
typedef __attribute__((ext_vector_type(8))) short bh8;   // 8 bf16 = 4 VGPR
typedef __attribute__((ext_vector_type(4))) float f4;    // MFMA acc

#define LOG2E 1.44269504088896f
#define QSCALE 0.18033688f   // 0.125 * log2(e), folded into Q at GEMM1 epilogue

__device__ inline u16 f2bf(float f) {
  union { float f; uint32_t u; } c; c.f = f;
  uint32_t u = c.u;
  return (u16)((u + 0x7fffu + ((u >> 16) & 1u)) >> 16);  // RNE
}

__device__ inline float fast_exp2(float x) {
#if __has_builtin(__builtin_amdgcn_exp2f)
  return __builtin_amdgcn_exp2f(x);
#else
  return exp2f(x);
#endif
}

#if __has_builtin(__builtin_amdgcn_global_load_lds)
#define GLD16(gp, lp) __builtin_amdgcn_global_load_lds( \
    (const __attribute__((address_space(1))) void*)(gp), \
    (__attribute__((address_space(3))) void*)(lp), 16, 0, 0)
#else
#define GLD16(gp, lp) do { *(bh8*)(lp) = *(const bh8*)(gp); } while (0)
#endif

// ---------------- convert / transpose ----------------

__global__ __launch_bounds__(256) void cvt_f32_bf16(const float* __restrict__ src,
                                                    u16* __restrict__ dst, int n4) {
  int i = blockIdx.x * 256 + threadIdx.x;
  if (i < n4) {
    float4 v = ((const float4*)src)[i];
    ushort4 o;
    o.x = f2bf(v.x); o.y = f2bf(v.y); o.z = f2bf(v.z); o.w = f2bf(v.w);
    ((ushort4*)dst)[i] = o;
  }
}

// src: K x N fp32 row-major -> dst: N x K bf16 row-major
__global__ __launch_bounds__(1024) void transpose_cvt(const float* __restrict__ src,
                                                      u16* __restrict__ dst, int K, int N) {
  __shared__ float tile[32][33];
  int n0 = blockIdx.x * 32, k0 = blockIdx.y * 32;
  int tx = threadIdx.x, ty = threadIdx.y;
  tile[ty][tx] = src[(size_t)(k0 + ty) * N + n0 + tx];
  __syncthreads();
  dst[(size_t)(n0 + ty) * K + k0 + tx] = f2bf(tile[tx][ty]);
}

// v [64][2048][64] bf16 -> vt [64][64][2048] bf16
__global__ __launch_bounds__(1024) void transpose_b16(const u16* __restrict__ src,
                                                      u16* __restrict__ dst) {
  __shared__ u16 t[32][33];
  int bh = blockIdx.z, l0 = blockIdx.y * 32, d0 = blockIdx.x * 32;
  int tx = threadIdx.x, ty = threadIdx.y;
  t[ty][tx] = src[((size_t)bh * 2048 + l0 + ty) * 64 + d0 + tx];
  __syncthreads();
  dst[((size_t)bh * 64 + d0 + ty) * 2048 + l0 + tx] = t[tx][ty];
}

// ---------------- GEMM mainloop (C = A @ Bt^T), 128x128 tile, BK=64 ----------------
__device__ inline void gemm_mainloop(const u16* __restrict__ A, const u16* __restrict__ Bt,
                                     int K, int m0, int n0,
                                     u16* As, u16* Bs, f4 acc[4][4]) {
  const int tid  = threadIdx.x;
  const int lane = tid & 63;
  const int quad = lane >> 4;
  const int ml   = lane & 15;
  const int wave = tid >> 6;
  const int wm   = (wave >> 1) * 64;
  const int wn   = (wave & 1) * 64;

#pragma unroll 1
  for (int k0 = 0; k0 < K; k0 += 64) {
#pragma unroll
    for (int r = 0; r < 4; ++r) {
      int chunk = r * 256 + tid;
      int row = chunk >> 3, cc = chunk & 7;
      int cg = cc ^ (row & 7);
      GLD16(A + (size_t)(m0 + row) * K + k0 + cg * 8, As + chunk * 8);
    }
#pragma unroll
    for (int r = 0; r < 4; ++r) {
      int chunk = r * 256 + tid;
      int row = chunk >> 3, cc = chunk & 7;
      int cg = cc ^ (row & 7);
      GLD16(Bt + (size_t)(n0 + row) * K + k0 + cg * 8, Bs + chunk * 8);
    }
    __syncthreads();
#pragma unroll
    for (int ks = 0; ks < 2; ++ks) {
      bh8 af[4], bfr[4];
      int cs = (ks * 4 + quad) ^ (ml & 7);
#pragma unroll
      for (int i = 0; i < 4; ++i) {
        int row = wm + i * 16 + ml;
        af[i] = *(const bh8*)(As + (row * 8 + cs) * 8);
      }
#pragma unroll
      for (int j = 0; j < 4; ++j) {
        int row = wn + j * 16 + ml;
        bfr[j] = *(const bh8*)(Bs + (row * 8 + cs) * 8);
      }
#pragma unroll
      for (int i = 0; i < 4; ++i)
#pragma unroll
        for (int j = 0; j < 4; ++j)
          acc[i][j] = __builtin_amdgcn_mfma_f32_16x16x32_bf16(af[i], bfr[j], acc[i][j], 0, 0, 0);
    }
    __syncthreads();
  }
}

// ---------------- GEMM1: qkv = x @ w_qkv + b ----------------
// q scaled by QSCALE; q,k,v all stored [bh][l][d] bf16 (v transposed later)
__global__ __launch_bounds__(256) void gemm_qkv(const u16* __restrict__ xb,
                                                const u16* __restrict__ wqt,
                                                const float* __restrict__ bqkv,
                                                u16* __restrict__ q, u16* __restrict__ k,
                                                u16* __restrict__ v) {
  __shared__ __align__(16) u16 smem[2 * 128 * 64];
  const f4 fzero = {0.f, 0.f, 0.f, 0.f};
  f4 acc[4][4];
#pragma unroll
  for (int i = 0; i < 4; ++i)
#pragma unroll
    for (int j = 0; j < 4; ++j) acc[i][j] = fzero;

  int m0 = blockIdx.y * 128, n0 = blockIdx.x * 128;
  gemm_mainloop(xb, wqt, 1024, m0, n0, smem, smem + 128 * 64, acc);

  const int lane = threadIdx.x & 63, wave = threadIdx.x >> 6;
  const int quad = lane >> 4, ml = lane & 15;
  const int wm = (wave >> 1) * 64, wn = (wave & 1) * 64;
  u16* dst = (n0 < 1024) ? q : ((n0 < 2048) ? k : v);
  float scale = (n0 < 1024) ? QSCALE : 1.0f;
#pragma unroll
  for (int j = 0; j < 4; ++j) {
    int nn = n0 + wn + j * 16 + ml;
    int h = (nn >> 6) & 15, d = nn & 63;
    float bias = bqkv[nn];
#pragma unroll
    for (int i = 0; i < 4; ++i) {
#pragma unroll
      for (int r = 0; r < 4; ++r) {
        int tok = m0 + wm + i * 16 + quad * 4 + r;
        int b = tok >> 11, l = tok & 2047;
        int bh = b * 16 + h;
        dst[((size_t)bh * 2048 + l) * 64 + d] = f2bf((acc[i][j][r] + bias) * scale);
      }
    }
  }
}

// ---------------- GEMM2: out = o @ w_out + b_out (fp32 out), 64x128 tile -----------
__global__ __launch_bounds__(256) void gemm_out64(const u16* __restrict__ ob,
                                                  const u16* __restrict__ wot,
                                                  const float* __restrict__ bout,
                                                  float* __restrict__ out) {
  __shared__ __align__(16) u16 As[64 * 64];
  __shared__ __align__(16) u16 Bs[128 * 64];
  const int tid  = threadIdx.x;
  const int lane = tid & 63;
  const int quad = lane >> 4;
  const int ml   = lane & 15;
  const int wave = tid >> 6;
  const int wm   = (wave >> 1) * 32;   // 2 wave-rows x 32
  const int wn   = (wave & 1) * 64;    // 2 wave-cols x 64
  const int m0 = blockIdx.y * 64, n0 = blockIdx.x * 128;

  const f4 fzero = {0.f, 0.f, 0.f, 0.f};
  f4 acc[2][4];
#pragma unroll
  for (int i = 0; i < 2; ++i)
#pragma unroll
    for (int j = 0; j < 4; ++j) acc[i][j] = fzero;

  const int srow = tid >> 3, scc = tid & 7;
  const int scg = scc ^ (srow & 7);

#pragma unroll 1
  for (int k0 = 0; k0 < 1024; k0 += 64) {
#pragma unroll
    for (int r = 0; r < 2; ++r) {
      int row = r * 32 + srow;   // [0,64)
      GLD16(ob + (size_t)(m0 + row) * 1024 + k0 + scg * 8, As + (row * 8 + scc) * 8);
    }
#pragma unroll
    for (int r = 0; r < 4; ++r) {
      int row = r * 32 + srow;   // [0,128)
      GLD16(wot + (size_t)(n0 + row) * 1024 + k0 + scg * 8, Bs + (row * 8 + scc) * 8);
    }
    __syncthreads();
#pragma unroll
    for (int ks = 0; ks < 2; ++ks) {
      int cs = (ks * 4 + quad) ^ (ml & 7);
      bh8 af[2], bfr[4];
#pragma unroll
      for (int i = 0; i < 2; ++i)
        af[i] = *(const bh8*)(As + ((wm + i * 16 + ml) * 8 + cs) * 8);
#pragma unroll
      for (int j = 0; j < 4; ++j)
        bfr[j] = *(const bh8*)(Bs + ((wn + j * 16 + ml) * 8 + cs) * 8);
#pragma unroll
      for (int i = 0; i < 2; ++i)
#pragma unroll
        for (int j = 0; j < 4; ++j)
          acc[i][j] = __builtin_amdgcn_mfma_f32_16x16x32_bf16(af[i], bfr[j], acc[i][j], 0, 0, 0);
    }
    __syncthreads();
  }

#pragma unroll
  for (int j = 0; j < 4; ++j) {
    int nn = n0 + wn + j * 16 + ml;
    float bias = bout[nn];
#pragma unroll
    for (int i = 0; i < 2; ++i)
#pragma unroll
      for (int r = 0; r < 4; ++r) {
        int tok = m0 + wm + i * 16 + quad * 4 + r;
        out[(size_t)tok * 1024 + nn] = acc[i][j][r] + bias;
      }
  }
}

// ---------------- flash attention v13: v12 minus cvt_pk ----------------------------
// Round-10 postmortem: v12 failed absmax 1.59e-2. This falsifies the round-7 "RTZ
// bias vs unrounded denominator" theory: v12's ones-MFMA denominator sums the SAME
// packed P (permutation/rounding invariant), so a pure rounding-bias would have
// cancelled. Evidence: cvt_pk present -> fail twice (1.04e-2, 1.59e-2); cvt_pk
// absent, same structure -> pass (v8/v10/v11). Conclusion: v_cvt_pk_bf16_f32's
// packing semantics differ from assumption (likely hi/lo operand order), permuting
// adjacent keys in the PV numerator only. The instruction is BANNED here; manual
// half-up pack (proven bit path) restored.
// Kept from v12 (orthogonal to numerics, algebra re-verified):
//  1. Bit1 slot permutation: write slot = (g*8 + jl*4 + 2*(qw&1) + (qw>>1)) ^ ml;
//     read slo = (g*8 + 4*(qr>>1) + (qr&1)) ^ ml, shi = slo^2. Bijective per
//     16-lane phase group (bank = 2*slot mod 32, region = ml*128B spans all 32
//     banks); read pair is 16B apart, per-lane direction varies -> no b128 merge.
//     Predicts SQ_LDS_BANK_CONFLICT 2.1M -> ~0 (key test of the merge theory).
//  2. ones-MFMA denominator (v5-proven with manual pack): deletes 32 lsum fadds +
//     2 end shuffles per wave-tile.
__global__ __launch_bounds__(256, 4) void attn(const u16* __restrict__ q,
                                               const u16* __restrict__ k,
                                               const u16* __restrict__ vt,
                                               u16* __restrict__ o) {
  __shared__ __align__(16) u16 Ks[2][64 * 64];    // row=key, 8 chunks, XOR swizzle
  __shared__ __align__(16) u16 Vs[2][64 * 64];    // row=d,   cols=key, XOR swizzle
  __shared__ __align__(16) u16 Pq[4][16 * 64];    // per-wave P, per-ml 128B regions
  const int bh = blockIdx.x;
  const int b = bh >> 4, h = bh & 15;
  const int tid = threadIdx.x;
  const int wave = tid >> 6, lane = tid & 63;
  const int quad = lane >> 4, ml = lane & 15;
  const int qw = blockIdx.y * 128 + wave * 32;
  const u16* qp = q + (size_t)bh * 2048 * 64;
  const u16* kp = k + (size_t)bh * 2048 * 64;
  const u16* vp = vt + (size_t)bh * 64 * 2048;
  const f4 fzero = {0.f, 0.f, 0.f, 0.f};

  const int mlx = ml & 7;    // XOR bits for Ks/Vs 16B-chunk swizzle

  // ones A-fragment for the li row-sum MFMA (bf16 1.0 in every element)
  bh8 ones;
#pragma unroll
  for (int t = 0; t < 8; ++t) ones[t] = (short)0x3F80;

  // Q fragments: B-operand, rows qw+g*16+ml, 16B contiguous
  bh8 qf[2][2];
#pragma unroll
  for (int g = 0; g < 2; ++g)
#pragma unroll
    for (int ks = 0; ks < 2; ++ks)
      qf[g][ks] = *(const bh8*)&qp[(size_t)(qw + g * 16 + ml) * 64 + ks * 32 + quad * 8];

  f4 oacc[2][4], liacc[2];
#pragma unroll
  for (int g = 0; g < 2; ++g) {
#pragma unroll
    for (int j = 0; j < 4; ++j) oacc[g][j] = fzero;
    liacc[g] = fzero;
  }

  // staging addresses (row/chunk decomposition identical to gemm_mainloop)
  const int srow = tid >> 3, scc = tid & 7;
  const int scg = scc ^ (srow & 7);
  u16* pq = &Pq[wave][ml * 64];   // this lane's 128B region: 16 slots x 8B

  // prologue: stage K+V tile 0 into buffer 0
#pragma unroll
  for (int r = 0; r < 2; ++r) {
    int row = r * 32 + srow;
    GLD16(kp + (size_t)row * 64 + scg * 8, &Ks[0][(row * 8 + scc) * 8]);
    GLD16(vp + (size_t)row * 2048 + scg * 8, &Vs[0][(row * 8 + scc) * 8]);
  }
  __syncthreads();

  int cur = 0;
#pragma unroll 1
  for (int t = 0; t < 32; ++t) {
    // stage next K+V tile into the other buffer (in flight until end-of-tile drain)
    if (t < 31) {
      int ktn = (t + 1) * 64;
#pragma unroll
      for (int r = 0; r < 2; ++r) {
        int row = r * 32 + srow;
        GLD16(kp + (size_t)(ktn + row) * 64 + scg * 8, &Ks[cur ^ 1][(row * 8 + scc) * 8]);
        GLD16(vp + (size_t)row * 2048 + ktn + scg * 8, &Vs[cur ^ 1][(row * 8 + scc) * 8]);
      }
    }

    // S^T = K @ Q^T from LDS: s[g][j][r] = S[q=qw+g*16+ml][kt + 16j + 4quad + r]
    f4 s[2][4];
#pragma unroll
    for (int g = 0; g < 2; ++g)
#pragma unroll
      for (int j = 0; j < 4; ++j) s[g][j] = fzero;
#pragma unroll
    for (int ks = 0; ks < 2; ++ks) {
      int cs = (ks * 4 + quad) ^ mlx;
      bh8 kf[4];
#pragma unroll
      for (int j = 0; j < 4; ++j)
        kf[j] = *(const bh8*)(&Ks[cur][((j * 16 + ml) * 8 + cs) * 8]);
#pragma unroll
      for (int j = 0; j < 4; ++j) {
        s[0][j] = __builtin_amdgcn_mfma_f32_16x16x32_bf16(kf[j], qf[0][ks], s[0][j], 0, 0, 0);
        s[1][j] = __builtin_amdgcn_mfma_f32_16x16x32_bf16(kf[j], qf[1][ks], s[1][j], 0, 0, 0);
      }
    }

    // two ks-phases: softmax keys [32ks,32ks+32) -> write -> pf read -> PV + li.
    // Pq slots reused across phases (same-wave DS in-order => WAR safe).
#pragma unroll
    for (int ks = 0; ks < 2; ++ks) {
      // p = exp2(s) -> bf16 via manual half-up pack (proven bit path)
#pragma unroll
      for (int g = 0; g < 2; ++g) {
#pragma unroll
        for (int jl = 0; jl < 2; ++jl) {
          int j = ks * 2 + jl;
          uint32_t w[4];
#pragma unroll
          for (int r = 0; r < 4; ++r) {
            float p = fast_exp2(s[g][j][r]);
            union { float f; uint32_t u; } c; c.f = p;
            c.u = (c.u + 0x8000u) & 0xFFFF0000u;
            w[r] = c.u;
          }
          uint2 pk;
          pk.x = (w[0] >> 16) | w[1];
          pk.y = (w[2] >> 16) | w[3];
          // slot: bit0 <- quad&1, bit1 <- quad>>1 (pair-distinction lives in bit1)
          int sl = (g * 8 + jl * 4 + 2 * (quad & 1) + (quad >> 1)) ^ ml;
          *(uint2*)(pq + (sl << 2)) = pk;
        }
      }

      // O^T += V^T @ P^T ; li += 1 @ P^T  (vf from LDS, reused for both groups;
      // pf via two b64 reads 16B apart -> unmergeable, conflict-free)
      int cs = (ks * 4 + quad) ^ mlx;
      bh8 vf[4];
#pragma unroll
      for (int j = 0; j < 4; ++j)
        vf[j] = *(const bh8*)(&Vs[cur][((j * 16 + ml) * 8 + cs) * 8]);
#pragma unroll
      for (int g = 0; g < 2; ++g) {
        int slo = (g * 8 + 4 * (quad >> 1) + (quad & 1)) ^ ml;
        int shi = slo ^ 2;
        uint2 lo = *(const uint2*)(pq + (slo << 2));
        uint2 hi = *(const uint2*)(pq + (shi << 2));
        union { uint32_t u[4]; bh8 v; } pf;
        pf.u[0] = lo.x; pf.u[1] = lo.y; pf.u[2] = hi.x; pf.u[3] = hi.y;
#pragma unroll
        for (int j = 0; j < 4; ++j)
          oacc[g][j] = __builtin_amdgcn_mfma_f32_16x16x32_bf16(vf[j], pf.v, oacc[g][j], 0, 0, 0);
        liacc[g] = __builtin_amdgcn_mfma_f32_16x16x32_bf16(ones, pf.v, liacc[g], 0, 0, 0);
      }
    }
    __syncthreads();   // drains K/V stage (vmcnt) + all LDS reads of buf[cur]
    cur ^= 1;
  }

  // li[g] came through the same bf16 P as the numerator; every acc row holds the
  // full row-sum for q=qw+g*16+ml (ones x P^T), so no cross-lane reduction needed.
#pragma unroll
  for (int g = 0; g < 2; ++g) {
    float inv = 1.0f / liacc[g][0];
    // store o as (b, l, h, d) bf16; lane holds q=qw+g*16+ml, d=16j+4quad+r
    size_t obase = (((size_t)b * 2048 + qw + g * 16 + ml) * 16 + h) * 64;
#pragma unroll
    for (int j = 0; j < 4; ++j) {
      ushort4 w;
      w.x = f2bf(oacc[g][j][0] * inv);
      w.y = f2bf(oacc[g][j][1] * inv);
      w.z = f2bf(oacc[g][j][2] * inv);
      w.w = f2bf(oacc[g][j][3] * inv);
      *(ushort4*)(o + obase + j * 16 + quad * 4) = w;
    }
  }
}

// ---------------- launch ----------------

extern "C" void kernel_launch(void* const* d_in, const int* in_sizes, int n_in,
                              void* d_out, int out_size, void* d_ws, size_t ws_size,
                              hipStream_t stream) {
  const float* x     = (const float*)d_in[0];
  const float* w_qkv = (const float*)d_in[1];
  const float* b_qkv = (const float*)d_in[2];
  const float* w_out = (const float*)d_in[3];
  const float* b_out = (const float*)d_in[4];
  float* out = (float*)d_out;

  u16* ws  = (u16*)d_ws;
  u16* xb  = ws;                                  // 8192*1024 (later reused for vt)
  u16* wqt = xb + (size_t)8192 * 1024;            // 3072*1024
  u16* wot = wqt + (size_t)3072 * 1024;           // 1024*1024
  u16* qb  = wot + (size_t)1024 * 1024;           // 64*2048*64
  u16* kb  = qb + (size_t)64 * 2048 * 64;
  u16* vb  = kb + (size_t)64 * 2048 * 64;
  u16* vtb = xb;   // xb dead after gemm_qkv
  u16* ob  = vb;   // v dead after transpose_b16

  cvt_f32_bf16<<<8192, 256, 0, stream>>>(x, xb, 8192 * 1024 / 4);
  transpose_cvt<<<dim3(96, 32), dim3(32, 32), 0, stream>>>(w_qkv, wqt, 1024, 3072);
  transpose_cvt<<<dim3(32, 32), dim3(32, 32), 0, stream>>>(w_out, wot, 1024, 1024);
  gemm_qkv<<<dim3(24, 64), 256, 0, stream>>>(xb, wqt, b_qkv, qb, kb, vb);
  transpose_b16<<<dim3(2, 64, 64), dim3(32, 32), 0, stream>>>(vb, vtb);
  attn<<<dim3(64, 16), 256, 0, stream>>>(qb, kb, vtb, ob);
  gemm_out64<<<dim3(8, 128), 256, 0, stream>>>(ob, wot, b_out, out);
}

// Round 12
// 277.046 us; speedup vs baseline: 1.0583x; 1.0371x over previous
//
#include <hip/hip_runtime.h>
#include <stdint.h>

typedef unsigned short u16;
typedef __attribute__((ext_vector_type(8))) short bh8;   // 8 bf16 = 4 VGPR
typedef __attribute__((ext_vector_type(4))) float f4;    // MFMA acc

#define LOG2E 1.44269504088896f
#define QSCALE 0.18033688f   // 0.125 * log2(e), folded into Q at GEMM1 epilogue

__device__ inline u16 f2bf(float f) {
  union { float f; uint32_t u; } c; c.f = f;
  uint32_t u = c.u;
  return (u16)((u + 0x7fffu + ((u >> 16) & 1u)) >> 16);  // RNE
}

__device__ inline float fast_exp2(float x) {
#if __has_builtin(__builtin_amdgcn_exp2f)
  return __builtin_amdgcn_exp2f(x);
#else
  return exp2f(x);
#endif
}

#if __has_builtin(__builtin_amdgcn_global_load_lds)
#define GLD16(gp, lp) __builtin_amdgcn_global_load_lds( \
    (const __attribute__((address_space(1))) void*)(gp), \
    (__attribute__((address_space(3))) void*)(lp), 16, 0, 0)
#else
#define GLD16(gp, lp) do { *(bh8*)(lp) = *(const bh8*)(gp); } while (0)
#endif

// ---------------- convert / transpose ----------------

__global__ __launch_bounds__(256) void cvt_f32_bf16(const float* __restrict__ src,
                                                    u16* __restrict__ dst, int n4) {
  int i = blockIdx.x * 256 + threadIdx.x;
  if (i < n4) {
    float4 v = ((const float4*)src)[i];
    ushort4 o;
    o.x = f2bf(v.x); o.y = f2bf(v.y); o.z = f2bf(v.z); o.w = f2bf(v.w);
    ((ushort4*)dst)[i] = o;
  }
}

// src: K x N fp32 row-major -> dst: N x K bf16 row-major
__global__ __launch_bounds__(1024) void transpose_cvt(const float* __restrict__ src,
                                                      u16* __restrict__ dst, int K, int N) {
  __shared__ float tile[32][33];
  int n0 = blockIdx.x * 32, k0 = blockIdx.y * 32;
  int tx = threadIdx.x, ty = threadIdx.y;
  tile[ty][tx] = src[(size_t)(k0 + ty) * N + n0 + tx];
  __syncthreads();
  dst[(size_t)(n0 + ty) * K + k0 + tx] = f2bf(tile[tx][ty]);
}

// ---------------- GEMM mainloop (C = A @ Bt^T), 128x128 tile, BK=64 ----------------
__device__ inline void gemm_mainloop(const u16* __restrict__ A, const u16* __restrict__ Bt,
                                     int K, int m0, int n0,
                                     u16* As, u16* Bs, f4 acc[4][4]) {
  const int tid  = threadIdx.x;
  const int lane = tid & 63;
  const int quad = lane >> 4;
  const int ml   = lane & 15;
  const int wave = tid >> 6;
  const int wm   = (wave >> 1) * 64;
  const int wn   = (wave & 1) * 64;

#pragma unroll 1
  for (int k0 = 0; k0 < K; k0 += 64) {
#pragma unroll
    for (int r = 0; r < 4; ++r) {
      int chunk = r * 256 + tid;
      int row = chunk >> 3, cc = chunk & 7;
      int cg = cc ^ (row & 7);
      GLD16(A + (size_t)(m0 + row) * K + k0 + cg * 8, As + chunk * 8);
    }
#pragma unroll
    for (int r = 0; r < 4; ++r) {
      int chunk = r * 256 + tid;
      int row = chunk >> 3, cc = chunk & 7;
      int cg = cc ^ (row & 7);
      GLD16(Bt + (size_t)(n0 + row) * K + k0 + cg * 8, Bs + chunk * 8);
    }
    __syncthreads();
#pragma unroll
    for (int ks = 0; ks < 2; ++ks) {
      bh8 af[4], bfr[4];
      int cs = (ks * 4 + quad) ^ (ml & 7);
#pragma unroll
      for (int i = 0; i < 4; ++i) {
        int row = wm + i * 16 + ml;
        af[i] = *(const bh8*)(As + (row * 8 + cs) * 8);
      }
#pragma unroll
      for (int j = 0; j < 4; ++j) {
        int row = wn + j * 16 + ml;
        bfr[j] = *(const bh8*)(Bs + (row * 8 + cs) * 8);
      }
#pragma unroll
      for (int i = 0; i < 4; ++i)
#pragma unroll
        for (int j = 0; j < 4; ++j)
          acc[i][j] = __builtin_amdgcn_mfma_f32_16x16x32_bf16(af[i], bfr[j], acc[i][j], 0, 0, 0);
    }
    __syncthreads();
  }
}

// ---------------- GEMM1: qkv = x @ w_qkv + b ----------------
// q scaled by QSCALE; q,k stored [bh][l][d]; V stored DIRECTLY TRANSPOSED
// [bh][d][l] (round-11 change: kills the transpose_b16 kernel + its 34MB HBM
// round-trip; consecutive r = consecutive l -> vectorized ushort4 stores; r never
// crosses a batch boundary since the store base is a multiple of 4; values are
// bit-identical: same f2bf on the same acc+bias).
__global__ __launch_bounds__(256) void gemm_qkv(const u16* __restrict__ xb,
                                                const u16* __restrict__ wqt,
                                                const float* __restrict__ bqkv,
                                                u16* __restrict__ q, u16* __restrict__ k,
                                                u16* __restrict__ v) {
  __shared__ __align__(16) u16 smem[2 * 128 * 64];
  const f4 fzero = {0.f, 0.f, 0.f, 0.f};
  f4 acc[4][4];
#pragma unroll
  for (int i = 0; i < 4; ++i)
#pragma unroll
    for (int j = 0; j < 4; ++j) acc[i][j] = fzero;

  int m0 = blockIdx.y * 128, n0 = blockIdx.x * 128;
  gemm_mainloop(xb, wqt, 1024, m0, n0, smem, smem + 128 * 64, acc);

  const int lane = threadIdx.x & 63, wave = threadIdx.x >> 6;
  const int quad = lane >> 4, ml = lane & 15;
  const int wm = (wave >> 1) * 64, wn = (wave & 1) * 64;
  if (n0 < 2048) {
    u16* dst = (n0 < 1024) ? q : k;
    float scale = (n0 < 1024) ? QSCALE : 1.0f;
#pragma unroll
    for (int j = 0; j < 4; ++j) {
      int nn = n0 + wn + j * 16 + ml;
      int h = (nn >> 6) & 15, d = nn & 63;
      float bias = bqkv[nn];
#pragma unroll
      for (int i = 0; i < 4; ++i) {
#pragma unroll
        for (int r = 0; r < 4; ++r) {
          int tok = m0 + wm + i * 16 + quad * 4 + r;
          int b = tok >> 11, l = tok & 2047;
          int bh = b * 16 + h;
          dst[((size_t)bh * 2048 + l) * 64 + d] = f2bf((acc[i][j][r] + bias) * scale);
        }
      }
    }
  } else {
    // V path: store transposed [bh][d][2048], 8B vector stores
#pragma unroll
    for (int j = 0; j < 4; ++j) {
      int nn = n0 + wn + j * 16 + ml;
      int h = (nn >> 6) & 15, d = nn & 63;
      float bias = bqkv[nn];
#pragma unroll
      for (int i = 0; i < 4; ++i) {
        int tok = m0 + wm + i * 16 + quad * 4;   // r=0 base; +r stays in-batch
        int b = tok >> 11, l = tok & 2047;
        int bh = b * 16 + h;
        ushort4 w;
        w.x = f2bf(acc[i][j][0] + bias);
        w.y = f2bf(acc[i][j][1] + bias);
        w.z = f2bf(acc[i][j][2] + bias);
        w.w = f2bf(acc[i][j][3] + bias);
        *(ushort4*)&v[((size_t)bh * 64 + d) * 2048 + l] = w;
      }
    }
  }
}

// ---------------- GEMM2: out = o @ w_out + b_out (fp32 out), 64x128 tile -----------
__global__ __launch_bounds__(256) void gemm_out64(const u16* __restrict__ ob,
                                                  const u16* __restrict__ wot,
                                                  const float* __restrict__ bout,
                                                  float* __restrict__ out) {
  __shared__ __align__(16) u16 As[64 * 64];
  __shared__ __align__(16) u16 Bs[128 * 64];
  const int tid  = threadIdx.x;
  const int lane = tid & 63;
  const int quad = lane >> 4;
  const int ml   = lane & 15;
  const int wave = tid >> 6;
  const int wm   = (wave >> 1) * 32;   // 2 wave-rows x 32
  const int wn   = (wave & 1) * 64;    // 2 wave-cols x 64
  const int m0 = blockIdx.y * 64, n0 = blockIdx.x * 128;

  const f4 fzero = {0.f, 0.f, 0.f, 0.f};
  f4 acc[2][4];
#pragma unroll
  for (int i = 0; i < 2; ++i)
#pragma unroll
    for (int j = 0; j < 4; ++j) acc[i][j] = fzero;

  const int srow = tid >> 3, scc = tid & 7;
  const int scg = scc ^ (srow & 7);

#pragma unroll 1
  for (int k0 = 0; k0 < 1024; k0 += 64) {
#pragma unroll
    for (int r = 0; r < 2; ++r) {
      int row = r * 32 + srow;   // [0,64)
      GLD16(ob + (size_t)(m0 + row) * 1024 + k0 + scg * 8, As + (row * 8 + scc) * 8);
    }
#pragma unroll
    for (int r = 0; r < 4; ++r) {
      int row = r * 32 + srow;   // [0,128)
      GLD16(wot + (size_t)(n0 + row) * 1024 + k0 + scg * 8, Bs + (row * 8 + scc) * 8);
    }
    __syncthreads();
#pragma unroll
    for (int ks = 0; ks < 2; ++ks) {
      int cs = (ks * 4 + quad) ^ (ml & 7);
      bh8 af[2], bfr[4];
#pragma unroll
      for (int i = 0; i < 2; ++i)
        af[i] = *(const bh8*)(As + ((wm + i * 16 + ml) * 8 + cs) * 8);
#pragma unroll
      for (int j = 0; j < 4; ++j)
        bfr[j] = *(const bh8*)(Bs + ((wn + j * 16 + ml) * 8 + cs) * 8);
#pragma unroll
      for (int i = 0; i < 2; ++i)
#pragma unroll
        for (int j = 0; j < 4; ++j)
          acc[i][j] = __builtin_amdgcn_mfma_f32_16x16x32_bf16(af[i], bfr[j], acc[i][j], 0, 0, 0);
    }
    __syncthreads();
  }

#pragma unroll
  for (int j = 0; j < 4; ++j) {
    int nn = n0 + wn + j * 16 + ml;
    float bias = bout[nn];
#pragma unroll
    for (int i = 0; i < 2; ++i)
#pragma unroll
      for (int r = 0; r < 4; ++r) {
        int tok = m0 + wm + i * 16 + quad * 4 + r;
        out[(size_t)tok * 1024 + nn] = acc[i][j][r] + bias;
      }
  }
}

// ---------------- flash attention v13 (unchanged: proven 95.1us, 0 conflicts) ------
// Conflict history: v10 (ml&14 swizzle) 4.19M; v11 (full-ml, adjacent read pair ->
// compiler b128 merge drops ml bit0) 2.10M; v13 (bit1-separated read pair,
// unmergeable) 0. Numerics: manual half-up pack + ones-MFMA denominator (same bf16
// P for num and den -> rounding bias cancels). v_cvt_pk_bf16_f32 BANNED (failed
// twice: packing semantics differ from assumption).
__global__ __launch_bounds__(256, 4) void attn(const u16* __restrict__ q,
                                               const u16* __restrict__ k,
                                               const u16* __restrict__ vt,
                                               u16* __restrict__ o) {
  __shared__ __align__(16) u16 Ks[2][64 * 64];    // row=key, 8 chunks, XOR swizzle
  __shared__ __align__(16) u16 Vs[2][64 * 64];    // row=d,   cols=key, XOR swizzle
  __shared__ __align__(16) u16 Pq[4][16 * 64];    // per-wave P, per-ml 128B regions
  const int bh = blockIdx.x;
  const int b = bh >> 4, h = bh & 15;
  const int tid = threadIdx.x;
  const int wave = tid >> 6, lane = tid & 63;
  const int quad = lane >> 4, ml = lane & 15;
  const int qw = blockIdx.y * 128 + wave * 32;
  const u16* qp = q + (size_t)bh * 2048 * 64;
  const u16* kp = k + (size_t)bh * 2048 * 64;
  const u16* vp = vt + (size_t)bh * 64 * 2048;
  const f4 fzero = {0.f, 0.f, 0.f, 0.f};

  const int mlx = ml & 7;    // XOR bits for Ks/Vs 16B-chunk swizzle

  // ones A-fragment for the li row-sum MFMA (bf16 1.0 in every element)
  bh8 ones;
#pragma unroll
  for (int t = 0; t < 8; ++t) ones[t] = (short)0x3F80;

  // Q fragments: B-operand, rows qw+g*16+ml, 16B contiguous
  bh8 qf[2][2];
#pragma unroll
  for (int g = 0; g < 2; ++g)
#pragma unroll
    for (int ks = 0; ks < 2; ++ks)
      qf[g][ks] = *(const bh8*)&qp[(size_t)(qw + g * 16 + ml) * 64 + ks * 32 + quad * 8];

  f4 oacc[2][4], liacc[2];
#pragma unroll
  for (int g = 0; g < 2; ++g) {
#pragma unroll
    for (int j = 0; j < 4; ++j) oacc[g][j] = fzero;
    liacc[g] = fzero;
  }

  // staging addresses (row/chunk decomposition identical to gemm_mainloop)
  const int srow = tid >> 3, scc = tid & 7;
  const int scg = scc ^ (srow & 7);
  u16* pq = &Pq[wave][ml * 64];   // this lane's 128B region: 16 slots x 8B

  // prologue: stage K+V tile 0 into buffer 0
#pragma unroll
  for (int r = 0; r < 2; ++r) {
    int row = r * 32 + srow;
    GLD16(kp + (size_t)row * 64 + scg * 8, &Ks[0][(row * 8 + scc) * 8]);
    GLD16(vp + (size_t)row * 2048 + scg * 8, &Vs[0][(row * 8 + scc) * 8]);
  }
  __syncthreads();

  int cur = 0;
#pragma unroll 1
  for (int t = 0; t < 32; ++t) {
    // stage next K+V tile into the other buffer (in flight until end-of-tile drain)
    if (t < 31) {
      int ktn = (t + 1) * 64;
#pragma unroll
      for (int r = 0; r < 2; ++r) {
        int row = r * 32 + srow;
        GLD16(kp + (size_t)(ktn + row) * 64 + scg * 8, &Ks[cur ^ 1][(row * 8 + scc) * 8]);
        GLD16(vp + (size_t)row * 2048 + ktn + scg * 8, &Vs[cur ^ 1][(row * 8 + scc) * 8]);
      }
    }

    // S^T = K @ Q^T from LDS: s[g][j][r] = S[q=qw+g*16+ml][kt + 16j + 4quad + r]
    f4 s[2][4];
#pragma unroll
    for (int g = 0; g < 2; ++g)
#pragma unroll
      for (int j = 0; j < 4; ++j) s[g][j] = fzero;
#pragma unroll
    for (int ks = 0; ks < 2; ++ks) {
      int cs = (ks * 4 + quad) ^ mlx;
      bh8 kf[4];
#pragma unroll
      for (int j = 0; j < 4; ++j)
        kf[j] = *(const bh8*)(&Ks[cur][((j * 16 + ml) * 8 + cs) * 8]);
#pragma unroll
      for (int j = 0; j < 4; ++j) {
        s[0][j] = __builtin_amdgcn_mfma_f32_16x16x32_bf16(kf[j], qf[0][ks], s[0][j], 0, 0, 0);
        s[1][j] = __builtin_amdgcn_mfma_f32_16x16x32_bf16(kf[j], qf[1][ks], s[1][j], 0, 0, 0);
      }
    }

    // two ks-phases: softmax keys [32ks,32ks+32) -> write -> pf read -> PV + li.
    // Pq slots reused across phases (same-wave DS in-order => WAR safe).
#pragma unroll
    for (int ks = 0; ks < 2; ++ks) {
      // p = exp2(s) -> bf16 via manual half-up pack (proven bit path)
#pragma unroll
      for (int g = 0; g < 2; ++g) {
#pragma unroll
        for (int jl = 0; jl < 2; ++jl) {
          int j = ks * 2 + jl;
          uint32_t w[4];
#pragma unroll
          for (int r = 0; r < 4; ++r) {
            float p = fast_exp2(s[g][j][r]);
            union { float f; uint32_t u; } c; c.f = p;
            c.u = (c.u + 0x8000u) & 0xFFFF0000u;
            w[r] = c.u;
          }
          uint2 pk;
          pk.x = (w[0] >> 16) | w[1];
          pk.y = (w[2] >> 16) | w[3];
          // slot: bit0 <- quad&1, bit1 <- quad>>1 (pair-distinction lives in bit1)
          int sl = (g * 8 + jl * 4 + 2 * (quad & 1) + (quad >> 1)) ^ ml;
          *(uint2*)(pq + (sl << 2)) = pk;
        }
      }

      // O^T += V^T @ P^T ; li += 1 @ P^T  (vf from LDS, reused for both groups;
      // pf via two b64 reads 16B apart -> unmergeable, conflict-free)
      int cs = (ks * 4 + quad) ^ mlx;
      bh8 vf[4];
#pragma unroll
      for (int j = 0; j < 4; ++j)
        vf[j] = *(const bh8*)(&Vs[cur][((j * 16 + ml) * 8 + cs) * 8]);
#pragma unroll
      for (int g = 0; g < 2; ++g) {
        int slo = (g * 8 + 4 * (quad >> 1) + (quad & 1)) ^ ml;
        int shi = slo ^ 2;
        uint2 lo = *(const uint2*)(pq + (slo << 2));
        uint2 hi = *(const uint2*)(pq + (shi << 2));
        union { uint32_t u[4]; bh8 v; } pf;
        pf.u[0] = lo.x; pf.u[1] = lo.y; pf.u[2] = hi.x; pf.u[3] = hi.y;
#pragma unroll
        for (int j = 0; j < 4; ++j)
          oacc[g][j] = __builtin_amdgcn_mfma_f32_16x16x32_bf16(vf[j], pf.v, oacc[g][j], 0, 0, 0);
        liacc[g] = __builtin_amdgcn_mfma_f32_16x16x32_bf16(ones, pf.v, liacc[g], 0, 0, 0);
      }
    }
    __syncthreads();   // drains K/V stage (vmcnt) + all LDS reads of buf[cur]
    cur ^= 1;
  }

  // li[g] came through the same bf16 P as the numerator; every acc row holds the
  // full row-sum for q=qw+g*16+ml (ones x P^T), so no cross-lane reduction needed.
#pragma unroll
  for (int g = 0; g < 2; ++g) {
    float inv = 1.0f / liacc[g][0];
    // store o as (b, l, h, d) bf16; lane holds q=qw+g*16+ml, d=16j+4quad+r
    size_t obase = (((size_t)b * 2048 + qw + g * 16 + ml) * 16 + h) * 64;
#pragma unroll
    for (int j = 0; j < 4; ++j) {
      ushort4 w;
      w.x = f2bf(oacc[g][j][0] * inv);
      w.y = f2bf(oacc[g][j][1] * inv);
      w.z = f2bf(oacc[g][j][2] * inv);
      w.w = f2bf(oacc[g][j][3] * inv);
      *(ushort4*)(o + obase + j * 16 + quad * 4) = w;
    }
  }
}

// ---------------- launch ----------------
// Workspace re-plumbed (no growth): gemm_qkv writes vt DIRECTLY into vb
// (transposed); attn writes o into xb (dead after gemm_qkv); gemm_out64 reads xb.
// transpose_b16 deleted (-34MB HBM round-trip, -1 launch).

extern "C" void kernel_launch(void* const* d_in, const int* in_sizes, int n_in,
                              void* d_out, int out_size, void* d_ws, size_t ws_size,
                              hipStream_t stream) {
  const float* x     = (const float*)d_in[0];
  const float* w_qkv = (const float*)d_in[1];
  const float* b_qkv = (const float*)d_in[2];
  const float* w_out = (const float*)d_in[3];
  const float* b_out = (const float*)d_in[4];
  float* out = (float*)d_out;

  u16* ws  = (u16*)d_ws;
  u16* xb  = ws;                                  // 8192*1024 (o reuses after gemm_qkv)
  u16* wqt = xb + (size_t)8192 * 1024;            // 3072*1024
  u16* wot = wqt + (size_t)3072 * 1024;           // 1024*1024
  u16* qb  = wot + (size_t)1024 * 1024;           // 64*2048*64
  u16* kb  = qb + (size_t)64 * 2048 * 64;
  u16* vb  = kb + (size_t)64 * 2048 * 64;         // vt [bh][d][l] (written directly)
  u16* ob  = xb;   // xb dead after gemm_qkv

  cvt_f32_bf16<<<8192, 256, 0, stream>>>(x, xb, 8192 * 1024 / 4);
  transpose_cvt<<<dim3(96, 32), dim3(32, 32), 0, stream>>>(w_qkv, wqt, 1024, 3072);
  transpose_cvt<<<dim3(32, 32), dim3(32, 32), 0, stream>>>(w_out, wot, 1024, 1024);
  gemm_qkv<<<dim3(24, 64), 256, 0, stream>>>(xb, wqt, b_qkv, qb, kb, vb);
  attn<<<dim3(64, 16), 256, 0, stream>>>(qb, kb, vb, ob);
  gemm_out64<<<dim3(8, 128), 256, 0, stream>>>(ob, wot, b_out, out);
}

// Round 13
// 274.886 us; speedup vs baseline: 1.0666x; 1.0079x over previous
//
#include <hip/hip_runtime.h>
#include <stdint.h>

typedef unsigned short u16;
typedef __attribute__((ext_vector_type(8))) short bh8;   // 8 bf16 = 4 VGPR
typedef __attribute__((ext_vector_type(4))) float f4;    // MFMA acc

#define LOG2E 1.44269504088896f
#define QSCALE 0.18033688f   // 0.125 * log2(e), folded into Q at GEMM1 epilogue

__device__ inline u16 f2bf(float f) {
  union { float f; uint32_t u; } c; c.f = f;
  uint32_t u = c.u;
  return (u16)((u + 0x7fffu + ((u >> 16) & 1u)) >> 16);  // RNE
}

__device__ inline float fast_exp2(float x) {
#if __has_builtin(__builtin_amdgcn_exp2f)
  return __builtin_amdgcn_exp2f(x);
#else
  return exp2f(x);
#endif
}

#if __has_builtin(__builtin_amdgcn_global_load_lds)
#define GLD16(gp, lp) __builtin_amdgcn_global_load_lds( \
    (const __attribute__((address_space(1))) void*)(gp), \
    (__attribute__((address_space(3))) void*)(lp), 16, 0, 0)
#else
#define GLD16(gp, lp) do { *(bh8*)(lp) = *(const bh8*)(gp); } while (0)
#endif

// ---------------- convert / transpose ----------------

__global__ __launch_bounds__(256) void cvt_f32_bf16(const float* __restrict__ src,
                                                    u16* __restrict__ dst, int n4) {
  int i = blockIdx.x * 256 + threadIdx.x;
  if (i < n4) {
    float4 v = ((const float4*)src)[i];
    ushort4 o;
    o.x = f2bf(v.x); o.y = f2bf(v.y); o.z = f2bf(v.z); o.w = f2bf(v.w);
    ((ushort4*)dst)[i] = o;
  }
}

// src: K x N fp32 row-major -> dst: N x K bf16 row-major
__global__ __launch_bounds__(1024) void transpose_cvt(const float* __restrict__ src,
                                                      u16* __restrict__ dst, int K, int N) {
  __shared__ float tile[32][33];
  int n0 = blockIdx.x * 32, k0 = blockIdx.y * 32;
  int tx = threadIdx.x, ty = threadIdx.y;
  tile[ty][tx] = src[(size_t)(k0 + ty) * N + n0 + tx];
  __syncthreads();
  dst[(size_t)(n0 + ty) * K + k0 + tx] = f2bf(tile[tx][ty]);
}

// ---------------- GEMM mainloop (C = A @ Bt^T), 128x128 tile, BK=64 ----------------
__device__ inline void gemm_mainloop(const u16* __restrict__ A, const u16* __restrict__ Bt,
                                     int K, int m0, int n0,
                                     u16* As, u16* Bs, f4 acc[4][4]) {
  const int tid  = threadIdx.x;
  const int lane = tid & 63;
  const int quad = lane >> 4;
  const int ml   = lane & 15;
  const int wave = tid >> 6;
  const int wm   = (wave >> 1) * 64;
  const int wn   = (wave & 1) * 64;

#pragma unroll 1
  for (int k0 = 0; k0 < K; k0 += 64) {
#pragma unroll
    for (int r = 0; r < 4; ++r) {
      int chunk = r * 256 + tid;
      int row = chunk >> 3, cc = chunk & 7;
      int cg = cc ^ (row & 7);
      GLD16(A + (size_t)(m0 + row) * K + k0 + cg * 8, As + chunk * 8);
    }
#pragma unroll
    for (int r = 0; r < 4; ++r) {
      int chunk = r * 256 + tid;
      int row = chunk >> 3, cc = chunk & 7;
      int cg = cc ^ (row & 7);
      GLD16(Bt + (size_t)(n0 + row) * K + k0 + cg * 8, Bs + chunk * 8);
    }
    __syncthreads();
#pragma unroll
    for (int ks = 0; ks < 2; ++ks) {
      bh8 af[4], bfr[4];
      int cs = (ks * 4 + quad) ^ (ml & 7);
#pragma unroll
      for (int i = 0; i < 4; ++i) {
        int row = wm + i * 16 + ml;
        af[i] = *(const bh8*)(As + (row * 8 + cs) * 8);
      }
#pragma unroll
      for (int j = 0; j < 4; ++j) {
        int row = wn + j * 16 + ml;
        bfr[j] = *(const bh8*)(Bs + (row * 8 + cs) * 8);
      }
#pragma unroll
      for (int i = 0; i < 4; ++i)
#pragma unroll
        for (int j = 0; j < 4; ++j)
          acc[i][j] = __builtin_amdgcn_mfma_f32_16x16x32_bf16(af[i], bfr[j], acc[i][j], 0, 0, 0);
    }
    __syncthreads();
  }
}

// ---------------- GEMM1: qkv = x @ w_qkv + b ----------------
// q scaled by QSCALE; q,k stored [bh][l][d]; V stored DIRECTLY TRANSPOSED [bh][d][l].
// Round-12 change: XCD-locality swizzle. 1-D grid 1536; xcd = wgid&7 (consecutive
// dispatch ids round-robin XCDs), each XCD owns a contiguous band of 8 m-tiles x
// all 24 n-tiles -> per-XCD A working set = 8 x 256KB = 2MB (L2-resident, was
// replicated 8x across XCDs = 128MB of L3->L2 refill); consecutive blocks within
// an XCD share the SAME A-panel (nt fastest). Bijective: wgid <-> (mt,nt).
__global__ __launch_bounds__(256) void gemm_qkv(const u16* __restrict__ xb,
                                                const u16* __restrict__ wqt,
                                                const float* __restrict__ bqkv,
                                                u16* __restrict__ q, u16* __restrict__ k,
                                                u16* __restrict__ v) {
  __shared__ __align__(16) u16 smem[2 * 128 * 64];
  const f4 fzero = {0.f, 0.f, 0.f, 0.f};
  f4 acc[4][4];
#pragma unroll
  for (int i = 0; i < 4; ++i)
#pragma unroll
    for (int j = 0; j < 4; ++j) acc[i][j] = fzero;

  const int wgid = blockIdx.x;                 // 0..1535
  const int xcd = wgid & 7, loc = wgid >> 3;   // loc in [0,192)
  const int mt = xcd * 8 + loc / 24;           // m-tile 0..63
  const int nt = loc % 24;                     // n-tile 0..23
  int m0 = mt * 128, n0 = nt * 128;
  gemm_mainloop(xb, wqt, 1024, m0, n0, smem, smem + 128 * 64, acc);

  const int lane = threadIdx.x & 63, wave = threadIdx.x >> 6;
  const int quad = lane >> 4, ml = lane & 15;
  const int wm = (wave >> 1) * 64, wn = (wave & 1) * 64;
  if (n0 < 2048) {
    u16* dst = (n0 < 1024) ? q : k;
    float scale = (n0 < 1024) ? QSCALE : 1.0f;
#pragma unroll
    for (int j = 0; j < 4; ++j) {
      int nn = n0 + wn + j * 16 + ml;
      int h = (nn >> 6) & 15, d = nn & 63;
      float bias = bqkv[nn];
#pragma unroll
      for (int i = 0; i < 4; ++i) {
#pragma unroll
        for (int r = 0; r < 4; ++r) {
          int tok = m0 + wm + i * 16 + quad * 4 + r;
          int b = tok >> 11, l = tok & 2047;
          int bh = b * 16 + h;
          dst[((size_t)bh * 2048 + l) * 64 + d] = f2bf((acc[i][j][r] + bias) * scale);
        }
      }
    }
  } else {
    // V path: store transposed [bh][d][2048], 8B vector stores
#pragma unroll
    for (int j = 0; j < 4; ++j) {
      int nn = n0 + wn + j * 16 + ml;
      int h = (nn >> 6) & 15, d = nn & 63;
      float bias = bqkv[nn];
#pragma unroll
      for (int i = 0; i < 4; ++i) {
        int tok = m0 + wm + i * 16 + quad * 4;   // r=0 base; +r stays in-batch
        int b = tok >> 11, l = tok & 2047;
        int bh = b * 16 + h;
        ushort4 w;
        w.x = f2bf(acc[i][j][0] + bias);
        w.y = f2bf(acc[i][j][1] + bias);
        w.z = f2bf(acc[i][j][2] + bias);
        w.w = f2bf(acc[i][j][3] + bias);
        *(ushort4*)&v[((size_t)bh * 64 + d) * 2048 + l] = w;
      }
    }
  }
}

// ---------------- GEMM2: out = o @ w_out + b_out (fp32 out), 64x128 tile -----------
// Round-12: same XCD-locality swizzle. 1-D grid 1024; each XCD owns 16 contiguous
// m-tiles x all 8 n-tiles -> per-XCD ob working set = 16 x 128KB = 2MB L2-resident
// (was ~16MB x 8 XCD replication); wot (2MB) L2-resident throughout.
__global__ __launch_bounds__(256) void gemm_out64(const u16* __restrict__ ob,
                                                  const u16* __restrict__ wot,
                                                  const float* __restrict__ bout,
                                                  float* __restrict__ out) {
  __shared__ __align__(16) u16 As[64 * 64];
  __shared__ __align__(16) u16 Bs[128 * 64];
  const int tid  = threadIdx.x;
  const int lane = tid & 63;
  const int quad = lane >> 4;
  const int ml   = lane & 15;
  const int wave = tid >> 6;
  const int wm   = (wave >> 1) * 32;   // 2 wave-rows x 32
  const int wn   = (wave & 1) * 64;    // 2 wave-cols x 64
  const int wgid = blockIdx.x;                  // 0..1023
  const int xcd = wgid & 7, loc = wgid >> 3;    // loc in [0,128)
  const int mt = xcd * 16 + loc / 8;            // m-tile 0..127
  const int nt = loc % 8;                       // n-tile 0..7
  const int m0 = mt * 64, n0 = nt * 128;

  const f4 fzero = {0.f, 0.f, 0.f, 0.f};
  f4 acc[2][4];
#pragma unroll
  for (int i = 0; i < 2; ++i)
#pragma unroll
    for (int j = 0; j < 4; ++j) acc[i][j] = fzero;

  const int srow = tid >> 3, scc = tid & 7;
  const int scg = scc ^ (srow & 7);

#pragma unroll 1
  for (int k0 = 0; k0 < 1024; k0 += 64) {
#pragma unroll
    for (int r = 0; r < 2; ++r) {
      int row = r * 32 + srow;   // [0,64)
      GLD16(ob + (size_t)(m0 + row) * 1024 + k0 + scg * 8, As + (row * 8 + scc) * 8);
    }
#pragma unroll
    for (int r = 0; r < 4; ++r) {
      int row = r * 32 + srow;   // [0,128)
      GLD16(wot + (size_t)(n0 + row) * 1024 + k0 + scg * 8, Bs + (row * 8 + scc) * 8);
    }
    __syncthreads();
#pragma unroll
    for (int ks = 0; ks < 2; ++ks) {
      int cs = (ks * 4 + quad) ^ (ml & 7);
      bh8 af[2], bfr[4];
#pragma unroll
      for (int i = 0; i < 2; ++i)
        af[i] = *(const bh8*)(As + ((wm + i * 16 + ml) * 8 + cs) * 8);
#pragma unroll
      for (int j = 0; j < 4; ++j)
        bfr[j] = *(const bh8*)(Bs + ((wn + j * 16 + ml) * 8 + cs) * 8);
#pragma unroll
      for (int i = 0; i < 2; ++i)
#pragma unroll
        for (int j = 0; j < 4; ++j)
          acc[i][j] = __builtin_amdgcn_mfma_f32_16x16x32_bf16(af[i], bfr[j], acc[i][j], 0, 0, 0);
    }
    __syncthreads();
  }

#pragma unroll
  for (int j = 0; j < 4; ++j) {
    int nn = n0 + wn + j * 16 + ml;
    float bias = bout[nn];
#pragma unroll
    for (int i = 0; i < 2; ++i)
#pragma unroll
      for (int r = 0; r < 4; ++r) {
        int tok = m0 + wm + i * 16 + quad * 4 + r;
        out[(size_t)tok * 1024 + nn] = acc[i][j][r] + bias;
      }
  }
}

// ---------------- flash attention v13 (frozen: proven 96us, 0 conflicts) -----------
// Grid already XCD-perfect by construction: bh = blockIdx.x fastest -> all 16
// q-tile blocks of head bh land on XCD bh%8; per-XCD K/V working set = 8 heads x
// 512KB = 4MB = exactly L2 (measured FETCH 26MB, near-ideal).
// Conflict history: v10 4.19M -> v11 2.10M (compiler b128-merge of adjacent read
// pair drops ml bit0) -> v13 0 (bit1-separated pair, unmergeable). Numerics:
// manual half-up pack + ones-MFMA denominator (same bf16 P for num and den ->
// rounding bias cancels). v_cvt_pk_bf16_f32 BANNED (failed twice).
__global__ __launch_bounds__(256, 4) void attn(const u16* __restrict__ q,
                                               const u16* __restrict__ k,
                                               const u16* __restrict__ vt,
                                               u16* __restrict__ o) {
  __shared__ __align__(16) u16 Ks[2][64 * 64];    // row=key, 8 chunks, XOR swizzle
  __shared__ __align__(16) u16 Vs[2][64 * 64];    // row=d,   cols=key, XOR swizzle
  __shared__ __align__(16) u16 Pq[4][16 * 64];    // per-wave P, per-ml 128B regions
  const int bh = blockIdx.x;
  const int b = bh >> 4, h = bh & 15;
  const int tid = threadIdx.x;
  const int wave = tid >> 6, lane = tid & 63;
  const int quad = lane >> 4, ml = lane & 15;
  const int qw = blockIdx.y * 128 + wave * 32;
  const u16* qp = q + (size_t)bh * 2048 * 64;
  const u16* kp = k + (size_t)bh * 2048 * 64;
  const u16* vp = vt + (size_t)bh * 64 * 2048;
  const f4 fzero = {0.f, 0.f, 0.f, 0.f};

  const int mlx = ml & 7;    // XOR bits for Ks/Vs 16B-chunk swizzle

  // ones A-fragment for the li row-sum MFMA (bf16 1.0 in every element)
  bh8 ones;
#pragma unroll
  for (int t = 0; t < 8; ++t) ones[t] = (short)0x3F80;

  // Q fragments: B-operand, rows qw+g*16+ml, 16B contiguous
  bh8 qf[2][2];
#pragma unroll
  for (int g = 0; g < 2; ++g)
#pragma unroll
    for (int ks = 0; ks < 2; ++ks)
      qf[g][ks] = *(const bh8*)&qp[(size_t)(qw + g * 16 + ml) * 64 + ks * 32 + quad * 8];

  f4 oacc[2][4], liacc[2];
#pragma unroll
  for (int g = 0; g < 2; ++g) {
#pragma unroll
    for (int j = 0; j < 4; ++j) oacc[g][j] = fzero;
    liacc[g] = fzero;
  }

  // staging addresses (row/chunk decomposition identical to gemm_mainloop)
  const int srow = tid >> 3, scc = tid & 7;
  const int scg = scc ^ (srow & 7);
  u16* pq = &Pq[wave][ml * 64];   // this lane's 128B region: 16 slots x 8B

  // prologue: stage K+V tile 0 into buffer 0
#pragma unroll
  for (int r = 0; r < 2; ++r) {
    int row = r * 32 + srow;
    GLD16(kp + (size_t)row * 64 + scg * 8, &Ks[0][(row * 8 + scc) * 8]);
    GLD16(vp + (size_t)row * 2048 + scg * 8, &Vs[0][(row * 8 + scc) * 8]);
  }
  __syncthreads();

  int cur = 0;
#pragma unroll 1
  for (int t = 0; t < 32; ++t) {
    // stage next K+V tile into the other buffer (in flight until end-of-tile drain)
    if (t < 31) {
      int ktn = (t + 1) * 64;
#pragma unroll
      for (int r = 0; r < 2; ++r) {
        int row = r * 32 + srow;
        GLD16(kp + (size_t)(ktn + row) * 64 + scg * 8, &Ks[cur ^ 1][(row * 8 + scc) * 8]);
        GLD16(vp + (size_t)row * 2048 + ktn + scg * 8, &Vs[cur ^ 1][(row * 8 + scc) * 8]);
      }
    }

    // S^T = K @ Q^T from LDS: s[g][j][r] = S[q=qw+g*16+ml][kt + 16j + 4quad + r]
    f4 s[2][4];
#pragma unroll
    for (int g = 0; g < 2; ++g)
#pragma unroll
      for (int j = 0; j < 4; ++j) s[g][j] = fzero;
#pragma unroll
    for (int ks = 0; ks < 2; ++ks) {
      int cs = (ks * 4 + quad) ^ mlx;
      bh8 kf[4];
#pragma unroll
      for (int j = 0; j < 4; ++j)
        kf[j] = *(const bh8*)(&Ks[cur][((j * 16 + ml) * 8 + cs) * 8]);
#pragma unroll
      for (int j = 0; j < 4; ++j) {
        s[0][j] = __builtin_amdgcn_mfma_f32_16x16x32_bf16(kf[j], qf[0][ks], s[0][j], 0, 0, 0);
        s[1][j] = __builtin_amdgcn_mfma_f32_16x16x32_bf16(kf[j], qf[1][ks], s[1][j], 0, 0, 0);
      }
    }

    // two ks-phases: softmax keys [32ks,32ks+32) -> write -> pf read -> PV + li.
    // Pq slots reused across phases (same-wave DS in-order => WAR safe).
#pragma unroll
    for (int ks = 0; ks < 2; ++ks) {
      // p = exp2(s) -> bf16 via manual half-up pack (proven bit path)
#pragma unroll
      for (int g = 0; g < 2; ++g) {
#pragma unroll
        for (int jl = 0; jl < 2; ++jl) {
          int j = ks * 2 + jl;
          uint32_t w[4];
#pragma unroll
          for (int r = 0; r < 4; ++r) {
            float p = fast_exp2(s[g][j][r]);
            union { float f; uint32_t u; } c; c.f = p;
            c.u = (c.u + 0x8000u) & 0xFFFF0000u;
            w[r] = c.u;
          }
          uint2 pk;
          pk.x = (w[0] >> 16) | w[1];
          pk.y = (w[2] >> 16) | w[3];
          // slot: bit0 <- quad&1, bit1 <- quad>>1 (pair-distinction lives in bit1)
          int sl = (g * 8 + jl * 4 + 2 * (quad & 1) + (quad >> 1)) ^ ml;
          *(uint2*)(pq + (sl << 2)) = pk;
        }
      }

      // O^T += V^T @ P^T ; li += 1 @ P^T  (vf from LDS, reused for both groups;
      // pf via two b64 reads 16B apart -> unmergeable, conflict-free)
      int cs = (ks * 4 + quad) ^ mlx;
      bh8 vf[4];
#pragma unroll
      for (int j = 0; j < 4; ++j)
        vf[j] = *(const bh8*)(&Vs[cur][((j * 16 + ml) * 8 + cs) * 8]);
#pragma unroll
      for (int g = 0; g < 2; ++g) {
        int slo = (g * 8 + 4 * (quad >> 1) + (quad & 1)) ^ ml;
        int shi = slo ^ 2;
        uint2 lo = *(const uint2*)(pq + (slo << 2));
        uint2 hi = *(const uint2*)(pq + (shi << 2));
        union { uint32_t u[4]; bh8 v; } pf;
        pf.u[0] = lo.x; pf.u[1] = lo.y; pf.u[2] = hi.x; pf.u[3] = hi.y;
#pragma unroll
        for (int j = 0; j < 4; ++j)
          oacc[g][j] = __builtin_amdgcn_mfma_f32_16x16x32_bf16(vf[j], pf.v, oacc[g][j], 0, 0, 0);
        liacc[g] = __builtin_amdgcn_mfma_f32_16x16x32_bf16(ones, pf.v, liacc[g], 0, 0, 0);
      }
    }
    __syncthreads();   // drains K/V stage (vmcnt) + all LDS reads of buf[cur]
    cur ^= 1;
  }

  // li[g] came through the same bf16 P as the numerator; every acc row holds the
  // full row-sum for q=qw+g*16+ml (ones x P^T), so no cross-lane reduction needed.
#pragma unroll
  for (int g = 0; g < 2; ++g) {
    float inv = 1.0f / liacc[g][0];
    // store o as (b, l, h, d) bf16; lane holds q=qw+g*16+ml, d=16j+4quad+r
    size_t obase = (((size_t)b * 2048 + qw + g * 16 + ml) * 16 + h) * 64;
#pragma unroll
    for (int j = 0; j < 4; ++j) {
      ushort4 w;
      w.x = f2bf(oacc[g][j][0] * inv);
      w.y = f2bf(oacc[g][j][1] * inv);
      w.z = f2bf(oacc[g][j][2] * inv);
      w.w = f2bf(oacc[g][j][3] * inv);
      *(ushort4*)(o + obase + j * 16 + quad * 4) = w;
    }
  }
}

// ---------------- launch ----------------
// gemm_qkv writes vt DIRECTLY into vb (transposed); attn writes o into xb (dead
// after gemm_qkv); gemm_out64 reads xb. GEMM grids are 1-D with in-kernel
// XCD-locality decomposition (round-12).

extern "C" void kernel_launch(void* const* d_in, const int* in_sizes, int n_in,
                              void* d_out, int out_size, void* d_ws, size_t ws_size,
                              hipStream_t stream) {
  const float* x     = (const float*)d_in[0];
  const float* w_qkv = (const float*)d_in[1];
  const float* b_qkv = (const float*)d_in[2];
  const float* w_out = (const float*)d_in[3];
  const float* b_out = (const float*)d_in[4];
  float* out = (float*)d_out;

  u16* ws  = (u16*)d_ws;
  u16* xb  = ws;                                  // 8192*1024 (o reuses after gemm_qkv)
  u16* wqt = xb + (size_t)8192 * 1024;            // 3072*1024
  u16* wot = wqt + (size_t)3072 * 1024;           // 1024*1024
  u16* qb  = wot + (size_t)1024 * 1024;           // 64*2048*64
  u16* kb  = qb + (size_t)64 * 2048 * 64;
  u16* vb  = kb + (size_t)64 * 2048 * 64;         // vt [bh][d][l] (written directly)
  u16* ob  = xb;   // xb dead after gemm_qkv

  cvt_f32_bf16<<<8192, 256, 0, stream>>>(x, xb, 8192 * 1024 / 4);
  transpose_cvt<<<dim3(96, 32), dim3(32, 32), 0, stream>>>(w_qkv, wqt, 1024, 3072);
  transpose_cvt<<<dim3(32, 32), dim3(32, 32), 0, stream>>>(w_out, wot, 1024, 1024);
  gemm_qkv<<<1536, 256, 0, stream>>>(xb, wqt, b_qkv, qb, kb, vb);
  attn<<<dim3(64, 16), 256, 0, stream>>>(qb, kb, vb, ob);
  gemm_out64<<<1024, 256, 0, stream>>>(ob, wot, b_out, out);
}

// Round 14
// 267.807 us; speedup vs baseline: 1.0948x; 1.0264x over previous
//
#include <hip/hip_runtime.h>
#include <stdint.h>

typedef unsigned short u16;
typedef __attribute__((ext_vector_type(8))) short bh8;   // 8 bf16 = 4 VGPR
typedef __attribute__((ext_vector_type(4))) float f4;    // MFMA acc

#define LOG2E 1.44269504088896f
#define QSCALE 0.18033688f   // 0.125 * log2(e), folded into Q at GEMM1 epilogue

__device__ inline u16 f2bf(float f) {
  union { float f; uint32_t u; } c; c.f = f;
  uint32_t u = c.u;
  return (u16)((u + 0x7fffu + ((u >> 16) & 1u)) >> 16);  // RNE
}

__device__ inline float fast_exp2(float x) {
#if __has_builtin(__builtin_amdgcn_exp2f)
  return __builtin_amdgcn_exp2f(x);
#else
  return exp2f(x);
#endif
}

#if __has_builtin(__builtin_amdgcn_global_load_lds)
#define GLD16(gp, lp) __builtin_amdgcn_global_load_lds( \
    (const __attribute__((address_space(1))) void*)(gp), \
    (__attribute__((address_space(3))) void*)(lp), 16, 0, 0)
#else
#define GLD16(gp, lp) do { *(bh8*)(lp) = *(const bh8*)(gp); } while (0)
#endif

#if __has_builtin(__builtin_amdgcn_s_setprio)
#define SETPRIO(n) __builtin_amdgcn_s_setprio(n)
#else
#define SETPRIO(n) do {} while (0)
#endif

// ---------------- merged prep: x cvt + both weight transposes ----------------------
// Round-14: one launch instead of three (saves 2 launch gaps + packs the tails).
// Blocks [0,8192): x f32->bf16 (float4/ushort4, 4 elems/thread, exact cover).
// Blocks [8192,11264): w_qkv (1024x3072) -> wqt (3072x1024) transpose+cvt.
// Blocks [11264,12288): w_out (1024x1024) -> wot transpose+cvt.
// Transpose tile 32x32 with 256 threads (4 rows/thread); LDS pad +1 -> both
// phases are 2-way bank aliased (free per m136); branch is block-uniform so the
// barriers inside the transpose branch are safe.

__device__ inline void transpose_tile_256(const float* __restrict__ src,
                                          u16* __restrict__ dst, int K, int N,
                                          int k0, int n0, float (*tile)[33]) {
  int tx = threadIdx.x & 31, ty0 = threadIdx.x >> 5;
#pragma unroll
  for (int s = 0; s < 4; ++s) {
    int ty = ty0 + s * 8;
    tile[ty][tx] = src[(size_t)(k0 + ty) * N + n0 + tx];
  }
  __syncthreads();
#pragma unroll
  for (int s = 0; s < 4; ++s) {
    int ty = ty0 + s * 8;
    dst[(size_t)(n0 + ty) * K + k0 + tx] = f2bf(tile[tx][ty]);
  }
}

__global__ __launch_bounds__(256) void prep(const float* __restrict__ x,
                                            u16* __restrict__ xb,
                                            const float* __restrict__ w_qkv,
                                            u16* __restrict__ wqt,
                                            const float* __restrict__ w_out,
                                            u16* __restrict__ wot) {
  __shared__ float tile[32][33];
  const int bid = blockIdx.x;
  if (bid < 8192) {
    int i = bid * 256 + threadIdx.x;
    float4 v = ((const float4*)x)[i];
    ushort4 o;
    o.x = f2bf(v.x); o.y = f2bf(v.y); o.z = f2bf(v.z); o.w = f2bf(v.w);
    ((ushort4*)xb)[i] = o;
  } else if (bid < 8192 + 3072) {
    int t = bid - 8192;                       // w_qkv: N=3072 (96 n-tiles), K=1024 (32 k-tiles)
    transpose_tile_256(w_qkv, wqt, 1024, 3072, (t / 96) * 32, (t % 96) * 32, tile);
  } else {
    int t = bid - 11264;                      // w_out: N=1024 (32 n-tiles), K=1024
    transpose_tile_256(w_out, wot, 1024, 1024, (t / 32) * 32, (t % 32) * 32, tile);
  }
}

// ---------------- GEMM mainloop (C = A @ Bt^T), 128x128 tile, BK=64 ----------------
__device__ inline void gemm_mainloop(const u16* __restrict__ A, const u16* __restrict__ Bt,
                                     int K, int m0, int n0,
                                     u16* As, u16* Bs, f4 acc[4][4]) {
  const int tid  = threadIdx.x;
  const int lane = tid & 63;
  const int quad = lane >> 4;
  const int ml   = lane & 15;
  const int wave = tid >> 6;
  const int wm   = (wave >> 1) * 64;
  const int wn   = (wave & 1) * 64;

#pragma unroll 1
  for (int k0 = 0; k0 < K; k0 += 64) {
#pragma unroll
    for (int r = 0; r < 4; ++r) {
      int chunk = r * 256 + tid;
      int row = chunk >> 3, cc = chunk & 7;
      int cg = cc ^ (row & 7);
      GLD16(A + (size_t)(m0 + row) * K + k0 + cg * 8, As + chunk * 8);
    }
#pragma unroll
    for (int r = 0; r < 4; ++r) {
      int chunk = r * 256 + tid;
      int row = chunk >> 3, cc = chunk & 7;
      int cg = cc ^ (row & 7);
      GLD16(Bt + (size_t)(n0 + row) * K + k0 + cg * 8, Bs + chunk * 8);
    }
    __syncthreads();
#pragma unroll
    for (int ks = 0; ks < 2; ++ks) {
      bh8 af[4], bfr[4];
      int cs = (ks * 4 + quad) ^ (ml & 7);
#pragma unroll
      for (int i = 0; i < 4; ++i) {
        int row = wm + i * 16 + ml;
        af[i] = *(const bh8*)(As + (row * 8 + cs) * 8);
      }
#pragma unroll
      for (int j = 0; j < 4; ++j) {
        int row = wn + j * 16 + ml;
        bfr[j] = *(const bh8*)(Bs + (row * 8 + cs) * 8);
      }
#pragma unroll
      for (int i = 0; i < 4; ++i)
#pragma unroll
        for (int j = 0; j < 4; ++j)
          acc[i][j] = __builtin_amdgcn_mfma_f32_16x16x32_bf16(af[i], bfr[j], acc[i][j], 0, 0, 0);
    }
    __syncthreads();
  }
}

// ---------------- GEMM1: qkv = x @ w_qkv + b ----------------
// q scaled by QSCALE; q,k stored [bh][l][d]; V stored DIRECTLY TRANSPOSED [bh][d][l].
// XCD-locality swizzle (round-12): xcd = wgid&7, contiguous m-band per XCD.
__global__ __launch_bounds__(256) void gemm_qkv(const u16* __restrict__ xb,
                                                const u16* __restrict__ wqt,
                                                const float* __restrict__ bqkv,
                                                u16* __restrict__ q, u16* __restrict__ k,
                                                u16* __restrict__ v) {
  __shared__ __align__(16) u16 smem[2 * 128 * 64];
  const f4 fzero = {0.f, 0.f, 0.f, 0.f};
  f4 acc[4][4];
#pragma unroll
  for (int i = 0; i < 4; ++i)
#pragma unroll
    for (int j = 0; j < 4; ++j) acc[i][j] = fzero;

  const int wgid = blockIdx.x;                 // 0..1535
  const int xcd = wgid & 7, loc = wgid >> 3;   // loc in [0,192)
  const int mt = xcd * 8 + loc / 24;           // m-tile 0..63
  const int nt = loc % 24;                     // n-tile 0..23
  int m0 = mt * 128, n0 = nt * 128;
  gemm_mainloop(xb, wqt, 1024, m0, n0, smem, smem + 128 * 64, acc);

  const int lane = threadIdx.x & 63, wave = threadIdx.x >> 6;
  const int quad = lane >> 4, ml = lane & 15;
  const int wm = (wave >> 1) * 64, wn = (wave & 1) * 64;
  if (n0 < 2048) {
    u16* dst = (n0 < 1024) ? q : k;
    float scale = (n0 < 1024) ? QSCALE : 1.0f;
#pragma unroll
    for (int j = 0; j < 4; ++j) {
      int nn = n0 + wn + j * 16 + ml;
      int h = (nn >> 6) & 15, d = nn & 63;
      float bias = bqkv[nn];
#pragma unroll
      for (int i = 0; i < 4; ++i) {
#pragma unroll
        for (int r = 0; r < 4; ++r) {
          int tok = m0 + wm + i * 16 + quad * 4 + r;
          int b = tok >> 11, l = tok & 2047;
          int bh = b * 16 + h;
          dst[((size_t)bh * 2048 + l) * 64 + d] = f2bf((acc[i][j][r] + bias) * scale);
        }
      }
    }
  } else {
    // V path: store transposed [bh][d][2048], 8B vector stores
#pragma unroll
    for (int j = 0; j < 4; ++j) {
      int nn = n0 + wn + j * 16 + ml;
      int h = (nn >> 6) & 15, d = nn & 63;
      float bias = bqkv[nn];
#pragma unroll
      for (int i = 0; i < 4; ++i) {
        int tok = m0 + wm + i * 16 + quad * 4;   // r=0 base; +r stays in-batch
        int b = tok >> 11, l = tok & 2047;
        int bh = b * 16 + h;
        ushort4 w;
        w.x = f2bf(acc[i][j][0] + bias);
        w.y = f2bf(acc[i][j][1] + bias);
        w.z = f2bf(acc[i][j][2] + bias);
        w.w = f2bf(acc[i][j][3] + bias);
        *(ushort4*)&v[((size_t)bh * 64 + d) * 2048 + l] = w;
      }
    }
  }
}

// ---------------- GEMM2: out = o @ w_out + b_out (fp32 out), 64x128 tile -----------
// XCD-locality swizzle (round-12).
__global__ __launch_bounds__(256) void gemm_out64(const u16* __restrict__ ob,
                                                  const u16* __restrict__ wot,
                                                  const float* __restrict__ bout,
                                                  float* __restrict__ out) {
  __shared__ __align__(16) u16 As[64 * 64];
  __shared__ __align__(16) u16 Bs[128 * 64];
  const int tid  = threadIdx.x;
  const int lane = tid & 63;
  const int quad = lane >> 4;
  const int ml   = lane & 15;
  const int wave = tid >> 6;
  const int wm   = (wave >> 1) * 32;   // 2 wave-rows x 32
  const int wn   = (wave & 1) * 64;    // 2 wave-cols x 64
  const int wgid = blockIdx.x;                  // 0..1023
  const int xcd = wgid & 7, loc = wgid >> 3;    // loc in [0,128)
  const int mt = xcd * 16 + loc / 8;            // m-tile 0..127
  const int nt = loc % 8;                       // n-tile 0..7
  const int m0 = mt * 64, n0 = nt * 128;

  const f4 fzero = {0.f, 0.f, 0.f, 0.f};
  f4 acc[2][4];
#pragma unroll
  for (int i = 0; i < 2; ++i)
#pragma unroll
    for (int j = 0; j < 4; ++j) acc[i][j] = fzero;

  const int srow = tid >> 3, scc = tid & 7;
  const int scg = scc ^ (srow & 7);

#pragma unroll 1
  for (int k0 = 0; k0 < 1024; k0 += 64) {
#pragma unroll
    for (int r = 0; r < 2; ++r) {
      int row = r * 32 + srow;   // [0,64)
      GLD16(ob + (size_t)(m0 + row) * 1024 + k0 + scg * 8, As + (row * 8 + scc) * 8);
    }
#pragma unroll
    for (int r = 0; r < 4; ++r) {
      int row = r * 32 + srow;   // [0,128)
      GLD16(wot + (size_t)(n0 + row) * 1024 + k0 + scg * 8, Bs + (row * 8 + scc) * 8);
    }
    __syncthreads();
#pragma unroll
    for (int ks = 0; ks < 2; ++ks) {
      int cs = (ks * 4 + quad) ^ (ml & 7);
      bh8 af[2], bfr[4];
#pragma unroll
      for (int i = 0; i < 2; ++i)
        af[i] = *(const bh8*)(As + ((wm + i * 16 + ml) * 8 + cs) * 8);
#pragma unroll
      for (int j = 0; j < 4; ++j)
        bfr[j] = *(const bh8*)(Bs + ((wn + j * 16 + ml) * 8 + cs) * 8);
#pragma unroll
      for (int i = 0; i < 2; ++i)
#pragma unroll
        for (int j = 0; j < 4; ++j)
          acc[i][j] = __builtin_amdgcn_mfma_f32_16x16x32_bf16(af[i], bfr[j], acc[i][j], 0, 0, 0);
    }
    __syncthreads();
  }

#pragma unroll
  for (int j = 0; j < 4; ++j) {
    int nn = n0 + wn + j * 16 + ml;
    float bias = bout[nn];
#pragma unroll
    for (int i = 0; i < 2; ++i)
#pragma unroll
      for (int r = 0; r < 4; ++r) {
        int tok = m0 + wm + i * 16 + quad * 4 + r;
        out[(size_t)tok * 1024 + nn] = acc[i][j][r] + bias;
      }
  }
}

// ---------------- flash attention v14: v13 + s_setprio around MFMA clusters --------
// v13 proven: 94us, 0 conflicts, absmax 4.88e-4. Round-14 adds T5 setprio(1)
// around the QK and PV MFMA bursts — pure CU-scheduler hint, cannot change values.
// Mechanism check: waves within a block are barrier-locked (m190-null-like) but 4
// independent blocks/CU give inter-block phase diversity (m191-positive-like);
// prediction 0..+5%.
// Conflict history: v10 4.19M -> v11 2.10M (compiler b128-merge of adjacent read
// pair drops ml bit0) -> v13 0 (bit1-separated pair, unmergeable). Numerics:
// manual half-up pack + ones-MFMA denominator (same bf16 P for num and den ->
// rounding bias cancels). v_cvt_pk_bf16_f32 BANNED (failed twice).
__global__ __launch_bounds__(256, 4) void attn(const u16* __restrict__ q,
                                               const u16* __restrict__ k,
                                               const u16* __restrict__ vt,
                                               u16* __restrict__ o) {
  __shared__ __align__(16) u16 Ks[2][64 * 64];    // row=key, 8 chunks, XOR swizzle
  __shared__ __align__(16) u16 Vs[2][64 * 64];    // row=d,   cols=key, XOR swizzle
  __shared__ __align__(16) u16 Pq[4][16 * 64];    // per-wave P, per-ml 128B regions
  const int bh = blockIdx.x;
  const int b = bh >> 4, h = bh & 15;
  const int tid = threadIdx.x;
  const int wave = tid >> 6, lane = tid & 63;
  const int quad = lane >> 4, ml = lane & 15;
  const int qw = blockIdx.y * 128 + wave * 32;
  const u16* qp = q + (size_t)bh * 2048 * 64;
  const u16* kp = k + (size_t)bh * 2048 * 64;
  const u16* vp = vt + (size_t)bh * 64 * 2048;
  const f4 fzero = {0.f, 0.f, 0.f, 0.f};

  const int mlx = ml & 7;    // XOR bits for Ks/Vs 16B-chunk swizzle

  // ones A-fragment for the li row-sum MFMA (bf16 1.0 in every element)
  bh8 ones;
#pragma unroll
  for (int t = 0; t < 8; ++t) ones[t] = (short)0x3F80;

  // Q fragments: B-operand, rows qw+g*16+ml, 16B contiguous
  bh8 qf[2][2];
#pragma unroll
  for (int g = 0; g < 2; ++g)
#pragma unroll
    for (int ks = 0; ks < 2; ++ks)
      qf[g][ks] = *(const bh8*)&qp[(size_t)(qw + g * 16 + ml) * 64 + ks * 32 + quad * 8];

  f4 oacc[2][4], liacc[2];
#pragma unroll
  for (int g = 0; g < 2; ++g) {
#pragma unroll
    for (int j = 0; j < 4; ++j) oacc[g][j] = fzero;
    liacc[g] = fzero;
  }

  // staging addresses (row/chunk decomposition identical to gemm_mainloop)
  const int srow = tid >> 3, scc = tid & 7;
  const int scg = scc ^ (srow & 7);
  u16* pq = &Pq[wave][ml * 64];   // this lane's 128B region: 16 slots x 8B

  // prologue: stage K+V tile 0 into buffer 0
#pragma unroll
  for (int r = 0; r < 2; ++r) {
    int row = r * 32 + srow;
    GLD16(kp + (size_t)row * 64 + scg * 8, &Ks[0][(row * 8 + scc) * 8]);
    GLD16(vp + (size_t)row * 2048 + scg * 8, &Vs[0][(row * 8 + scc) * 8]);
  }
  __syncthreads();

  int cur = 0;
#pragma unroll 1
  for (int t = 0; t < 32; ++t) {
    // stage next K+V tile into the other buffer (in flight until end-of-tile drain)
    if (t < 31) {
      int ktn = (t + 1) * 64;
#pragma unroll
      for (int r = 0; r < 2; ++r) {
        int row = r * 32 + srow;
        GLD16(kp + (size_t)(ktn + row) * 64 + scg * 8, &Ks[cur ^ 1][(row * 8 + scc) * 8]);
        GLD16(vp + (size_t)row * 2048 + ktn + scg * 8, &Vs[cur ^ 1][(row * 8 + scc) * 8]);
      }
    }

    // S^T = K @ Q^T from LDS: s[g][j][r] = S[q=qw+g*16+ml][kt + 16j + 4quad + r]
    f4 s[2][4];
#pragma unroll
    for (int g = 0; g < 2; ++g)
#pragma unroll
      for (int j = 0; j < 4; ++j) s[g][j] = fzero;
#pragma unroll
    for (int ks = 0; ks < 2; ++ks) {
      int cs = (ks * 4 + quad) ^ mlx;
      bh8 kf[4];
#pragma unroll
      for (int j = 0; j < 4; ++j)
        kf[j] = *(const bh8*)(&Ks[cur][((j * 16 + ml) * 8 + cs) * 8]);
      SETPRIO(1);
#pragma unroll
      for (int j = 0; j < 4; ++j) {
        s[0][j] = __builtin_amdgcn_mfma_f32_16x16x32_bf16(kf[j], qf[0][ks], s[0][j], 0, 0, 0);
        s[1][j] = __builtin_amdgcn_mfma_f32_16x16x32_bf16(kf[j], qf[1][ks], s[1][j], 0, 0, 0);
      }
      SETPRIO(0);
    }

    // two ks-phases: softmax keys [32ks,32ks+32) -> write -> pf read -> PV + li.
    // Pq slots reused across phases (same-wave DS in-order => WAR safe).
#pragma unroll
    for (int ks = 0; ks < 2; ++ks) {
      // p = exp2(s) -> bf16 via manual half-up pack (proven bit path)
#pragma unroll
      for (int g = 0; g < 2; ++g) {
#pragma unroll
        for (int jl = 0; jl < 2; ++jl) {
          int j = ks * 2 + jl;
          uint32_t w[4];
#pragma unroll
          for (int r = 0; r < 4; ++r) {
            float p = fast_exp2(s[g][j][r]);
            union { float f; uint32_t u; } c; c.f = p;
            c.u = (c.u + 0x8000u) & 0xFFFF0000u;
            w[r] = c.u;
          }
          uint2 pk;
          pk.x = (w[0] >> 16) | w[1];
          pk.y = (w[2] >> 16) | w[3];
          // slot: bit0 <- quad&1, bit1 <- quad>>1 (pair-distinction lives in bit1)
          int sl = (g * 8 + jl * 4 + 2 * (quad & 1) + (quad >> 1)) ^ ml;
          *(uint2*)(pq + (sl << 2)) = pk;
        }
      }

      // O^T += V^T @ P^T ; li += 1 @ P^T  (vf from LDS, reused for both groups;
      // pf via two b64 reads 16B apart -> unmergeable, conflict-free)
      int cs = (ks * 4 + quad) ^ mlx;
      bh8 vf[4];
#pragma unroll
      for (int j = 0; j < 4; ++j)
        vf[j] = *(const bh8*)(&Vs[cur][((j * 16 + ml) * 8 + cs) * 8]);
#pragma unroll
      for (int g = 0; g < 2; ++g) {
        int slo = (g * 8 + 4 * (quad >> 1) + (quad & 1)) ^ ml;
        int shi = slo ^ 2;
        uint2 lo = *(const uint2*)(pq + (slo << 2));
        uint2 hi = *(const uint2*)(pq + (shi << 2));
        union { uint32_t u[4]; bh8 v; } pf;
        pf.u[0] = lo.x; pf.u[1] = lo.y; pf.u[2] = hi.x; pf.u[3] = hi.y;
        SETPRIO(1);
#pragma unroll
        for (int j = 0; j < 4; ++j)
          oacc[g][j] = __builtin_amdgcn_mfma_f32_16x16x32_bf16(vf[j], pf.v, oacc[g][j], 0, 0, 0);
        liacc[g] = __builtin_amdgcn_mfma_f32_16x16x32_bf16(ones, pf.v, liacc[g], 0, 0, 0);
        SETPRIO(0);
      }
    }
    __syncthreads();   // drains K/V stage (vmcnt) + all LDS reads of buf[cur]
    cur ^= 1;
  }

  // li[g] came through the same bf16 P as the numerator; every acc row holds the
  // full row-sum for q=qw+g*16+ml (ones x P^T), so no cross-lane reduction needed.
#pragma unroll
  for (int g = 0; g < 2; ++g) {
    float inv = 1.0f / liacc[g][0];
    // store o as (b, l, h, d) bf16; lane holds q=qw+g*16+ml, d=16j+4quad+r
    size_t obase = (((size_t)b * 2048 + qw + g * 16 + ml) * 16 + h) * 64;
#pragma unroll
    for (int j = 0; j < 4; ++j) {
      ushort4 w;
      w.x = f2bf(oacc[g][j][0] * inv);
      w.y = f2bf(oacc[g][j][1] * inv);
      w.z = f2bf(oacc[g][j][2] * inv);
      w.w = f2bf(oacc[g][j][3] * inv);
      *(ushort4*)(o + obase + j * 16 + quad * 4) = w;
    }
  }
}

// ---------------- launch ----------------
// prep = merged cvt + weight transposes (1 launch, was 3). gemm_qkv writes vt
// DIRECTLY into vb (transposed); attn writes o into xb (dead after gemm_qkv);
// gemm_out64 reads xb. GEMM grids 1-D with in-kernel XCD decomposition.

extern "C" void kernel_launch(void* const* d_in, const int* in_sizes, int n_in,
                              void* d_out, int out_size, void* d_ws, size_t ws_size,
                              hipStream_t stream) {
  const float* x     = (const float*)d_in[0];
  const float* w_qkv = (const float*)d_in[1];
  const float* b_qkv = (const float*)d_in[2];
  const float* w_out = (const float*)d_in[3];
  const float* b_out = (const float*)d_in[4];
  float* out = (float*)d_out;

  u16* ws  = (u16*)d_ws;
  u16* xb  = ws;                                  // 8192*1024 (o reuses after gemm_qkv)
  u16* wqt = xb + (size_t)8192 * 1024;            // 3072*1024
  u16* wot = wqt + (size_t)3072 * 1024;           // 1024*1024
  u16* qb  = wot + (size_t)1024 * 1024;           // 64*2048*64
  u16* kb  = qb + (size_t)64 * 2048 * 64;
  u16* vb  = kb + (size_t)64 * 2048 * 64;         // vt [bh][d][l] (written directly)
  u16* ob  = xb;   // xb dead after gemm_qkv

  prep<<<12288, 256, 0, stream>>>(x, xb, w_qkv, wqt, w_out, wot);
  gemm_qkv<<<1536, 256, 0, stream>>>(xb, wqt, b_qkv, qb, kb, vb);
  attn<<<dim3(64, 16), 256, 0, stream>>>(qb, kb, vb, ob);
  gemm_out64<<<1024, 256, 0, stream>>>(ob, wot, b_out, out);
}